// Round 10
// baseline (730.858 us; speedup 1.0000x reference)
//
#include <hip/hip_runtime.h>
#include <cmath>

typedef short short8 __attribute__((ext_vector_type(8)));
typedef float floatx4 __attribute__((ext_vector_type(4)));

#define T_LEN 4096
#define HC 256
#define NPOS (32 * 4096)
#define OUT_ELEMS (32 * 4 * 4096)

__device__ __forceinline__ ushort f2bf(float f) {
    uint u = __float_as_uint(f);
    u += 0x7FFFu + ((u >> 16) & 1u);
    return (ushort)(u >> 16);
}
__device__ __forceinline__ float bf2f(ushort u) {
    return __uint_as_float(((uint)u) << 16);
}
__device__ __forceinline__ uint addbf2(uint a, uint b) {
    const float lo = bf2f((ushort)(a & 0xffffu)) + bf2f((ushort)(b & 0xffffu));
    const float hi = bf2f((ushort)(a >> 16)) + bf2f((ushort)(b >> 16));
    return (uint)f2bf(lo) | ((uint)f2bf(hi) << 16);
}
// fast tanh-form gelu: 8 instr, no branches; |err vs exact-erf gelu| <~1.5e-3
__device__ __forceinline__ float gelu_f(float x) {
    const float x2 = x * x;
    const float w = fmaf(0.044715f * x2, x, x);
    const float e = __builtin_amdgcn_exp2f(2.3022084f * w);
    const float r = __builtin_amdgcn_rcpf(1.f + e);
    return fmaf(-x, r, x);
}
__device__ __forceinline__ float softplus_f(float x) {
    return (x > 20.f) ? x : log1pf(expf(x));
}
__device__ __forceinline__ void load4bf(const ushort* p, float m, float* o) {
    uint2 r = *(const uint2*)p;
    o[0] = bf2f((ushort)(r.x & 0xffffu)) * m;
    o[1] = bf2f((ushort)(r.x >> 16)) * m;
    o[2] = bf2f((ushort)(r.y & 0xffffu)) * m;
    o[3] = bf2f((ushort)(r.y >> 16)) * m;
}

// ---------------------------------------------------------------- prep ----
__global__ __launch_bounds__(256) void prep_kernel(
    const float* __restrict__ cw, const float* __restrict__ pw,
    ushort* __restrict__ wbf, ushort* __restrict__ pwbf)
{
    int idx = blockIdx.x * 256 + threadIdx.x;
    if (idx < 4 * 256 * 256) {
        wbf[idx] = f2bf(cw[idx]);
    } else if (idx < 4 * 256 * 256 + 64 * 256) {
        int j = idx - 4 * 256 * 256;
        int row = j >> 8, c = j & 255;
        pwbf[j] = (row < 58) ? f2bf(pw[row * 256 + c]) : (ushort)0;
    }
}

// ----------------------------------------------------------------- pre ----
__global__ __launch_bounds__(256) void pre_kernel(
    const float* __restrict__ x, const float* __restrict__ mask,
    const float* __restrict__ pre_w, const float* __restrict__ pre_b,
    ushort* __restrict__ h, float* __restrict__ out)
{
    const int t = threadIdx.x;
    const int p0 = blockIdx.x * 2;
    const int p = p0 + (t >> 7);
    const int o = (t & 127) * 2;
    const int b = p >> 12;
    const int tt = p & 4095;
    const float xa = x[b * 16384 + tt];
    const float xb = x[b * 16384 + 4096 + tt];
    const float4 w = *(const float4*)(pre_w + 2 * o);
    const float v0 = w.x * xa + w.y * xb + pre_b[o];
    const float v1 = w.z * xa + w.w * xb + pre_b[o + 1];
    const uint pk = (uint)f2bf(v0) | ((uint)f2bf(v1) << 16);
    *(uint*)(h + (size_t)p * HC + o) = pk;
    if (t < 4) {
        const int pp = p0 + (t >> 1);
        const int bb = pp >> 12, t2 = pp & 4095;
        const int ch = t & 1;
        out[bb * 16384 + ch * 4096 + t2] = x[bb * 16384 + ch * 4096 + t2] * mask[bb * 4096 + t2];
    }
    if (blockIdx.x == 0 && t >= 64 && t < 96) out[OUT_ELEMS + (t - 64)] = 0.f;
}

// ---------------------------------------------------------------- dwln ----
// (unchanged — known good) dwconv(dil)+LN(n1)+gelu -> yg (bf16).
__global__ __launch_bounds__(256, 6) void dwln_kernel(
    const ushort* __restrict__ hin, ushort* __restrict__ yg,
    const float* __restrict__ sep_w, const float* __restrict__ sep_b,
    const float* __restrict__ n1g, const float* __restrict__ n1b,
    const float* __restrict__ mask, int dil)
{
    const int tid = threadIdx.x;
    const int lane = tid & 63;
    const int wv = tid >> 6;
    const int P = blockIdx.x;
    const int L = (P & 7) * 512 + (P >> 3);
    const int b = L >> 7;
    const int t0 = (L & 127) << 5;
    const float* maskb = mask + b * T_LEN;
    const size_t hbase = (size_t)b * T_LEN * HC;

    const int c0 = lane * 4;
    float sw[12];
    *(float4*)(sw + 0) = *(const float4*)(sep_w + c0 * 3 + 0);
    *(float4*)(sw + 4) = *(const float4*)(sep_w + c0 * 3 + 4);
    *(float4*)(sw + 8) = *(const float4*)(sep_w + c0 * 3 + 8);
    float sbv[4], g1v[4], b1v[4];
    *(float4*)sbv = *(const float4*)(sep_b + c0);
    *(float4*)g1v = *(const float4*)(n1g + c0);
    *(float4*)b1v = *(const float4*)(n1b + c0);

    for (int mm = 0; mm < 8; mm += 2) {
        float v[2][4];
        float s[2], q[2];
        #pragma unroll
        for (int u = 0; u < 2; ++u) {
            const int t = t0 + wv * 8 + mm + u;
            float hm[4] = {0.f, 0.f, 0.f, 0.f};
            float hp[4] = {0.f, 0.f, 0.f, 0.f};
            float hc[4];
            load4bf(hin + hbase + (size_t)t * HC + c0, maskb[t], hc);
            if (t >= dil)
                load4bf(hin + hbase + (size_t)(t - dil) * HC + c0, maskb[t - dil], hm);
            if (t + dil < T_LEN)
                load4bf(hin + hbase + (size_t)(t + dil) * HC + c0, maskb[t + dil], hp);
            s[u] = 0.f; q[u] = 0.f;
            #pragma unroll
            for (int j = 0; j < 4; ++j) {
                const float vv = sw[3 * j] * hm[j] + sw[3 * j + 1] * hc[j]
                               + sw[3 * j + 2] * hp[j] + sbv[j];
                v[u][j] = vv;
                s[u] += vv;
                q[u] += vv * vv;
            }
        }
        #pragma unroll
        for (int d = 32; d > 0; d >>= 1) {
            s[0] += __shfl_xor(s[0], d, 64);
            q[0] += __shfl_xor(q[0], d, 64);
            s[1] += __shfl_xor(s[1], d, 64);
            q[1] += __shfl_xor(q[1], d, 64);
        }
        #pragma unroll
        for (int u = 0; u < 2; ++u) {
            const int t = t0 + wv * 8 + mm + u;
            const float mean = s[u] * (1.f / 256.f);
            const float var = q[u] * (1.f / 256.f) - mean * mean;
            const float rs = rsqrtf(var + 1e-5f);
            const float y0 = gelu_f((v[u][0] - mean) * rs * g1v[0] + b1v[0]);
            const float y1 = gelu_f((v[u][1] - mean) * rs * g1v[1] + b1v[1]);
            const float y2 = gelu_f((v[u][2] - mean) * rs * g1v[2] + b1v[2]);
            const float y3 = gelu_f((v[u][3] - mean) * rs * g1v[3] + b1v[3]);
            const uint pk0 = (uint)f2bf(y0) | ((uint)f2bf(y1) << 16);
            const uint pk1 = (uint)f2bf(y2) | ((uint)f2bf(y3) << 16);
            *(uint2*)(yg + hbase + (size_t)t * HC + c0) = make_uint2(pk0, pk1);
        }
    }
}

// ---------------------------------------------------------------- gemm ----
// 32-row blocks (grid 4096, same L-swizzle as dwln so y is XCD-local).
// Wave = ALL 32 rows x 64-col quarter: acc 8 floatx4 = 32 AGPR ->
// bounds(256,4) = 4 waves/SIMD (R9 was 3; occupancy is the BW lever).
// A-frags read direct from yg (no staging barrier, R9-proven); A duplicated
// across the 4 waves but L2-hot. LN(n2) split 4-way via ssum[32][4].
__global__ __launch_bounds__(256, 4) void gemm_kernel(
    const ushort* __restrict__ yg, const ushort* __restrict__ hin,
    ushort* __restrict__ hout, const ushort* __restrict__ wbf,
    const float* __restrict__ conv1_b,
    const float* __restrict__ n2g, const float* __restrict__ n2b)
{
    __shared__ __align__(16) ushort ylds[32 * 264];
    __shared__ float ssum[32][4];
    __shared__ float ssq[32][4];

    const int tid = threadIdx.x;
    const int lane = tid & 63;
    const int wv = tid >> 6;
    const int P = blockIdx.x;
    const int L = (P & 7) * 512 + (P >> 3);
    const int b = L >> 7;
    const int t0 = (L & 127) << 5;
    const size_t hbase = (size_t)b * T_LEN * HC;

    const int lw = lane & 15;
    const int quad = lane >> 4;
    floatx4 acc[2][4];
    #pragma unroll
    for (int m = 0; m < 2; ++m)
        #pragma unroll
        for (int n = 0; n < 4; ++n) acc[m][n] = (floatx4){0.f, 0.f, 0.f, 0.f};

    const ushort* wb = wbf + (wv * 64 + lw) * 256 + quad * 8;
    const ushort* ya0 = yg + hbase + (size_t)(t0 + lw) * HC + quad * 8;
    const ushort* ya1 = ya0 + 16 * HC;
    #pragma unroll
    for (int kt = 0; kt < 8; ++kt) {
        short8 a0 = *(const short8*)(ya0 + kt * 32);
        short8 a1 = *(const short8*)(ya1 + kt * 32);
        #pragma unroll
        for (int n = 0; n < 4; ++n) {
            short8 bb = *(const short8*)(wb + n * 4096 + kt * 32);
            acc[0][n] = __builtin_amdgcn_mfma_f32_16x16x32_bf16(a0, bb, acc[0][n], 0, 0, 0);
            acc[1][n] = __builtin_amdgcn_mfma_f32_16x16x32_bf16(a1, bb, acc[1][n], 0, 0, 0);
        }
    }

    // ---- residual prefetch: overlaps the LN epilogue below ----
    uint4 hv[4];
    #pragma unroll
    for (int jj = 0; jj < 4; ++jj) {
        const int idx = jj * 256 + tid;           // 1024 chunks of 16B
        const int row = idx >> 5, seg = idx & 31;
        hv[jj] = *(const uint4*)(hin + hbase + (size_t)(t0 + row) * HC + seg * 8);
    }

    // ---- epilogue: bias + split LN(n2) over 4 col quarters ----
    float sum[2][4] = {{0, 0, 0, 0}, {0, 0, 0, 0}};
    float sq[2][4] = {{0, 0, 0, 0}, {0, 0, 0, 0}};
    #pragma unroll
    for (int n = 0; n < 4; ++n) {
        const float cb = conv1_b[wv * 64 + n * 16 + lw];
        #pragma unroll
        for (int m = 0; m < 2; ++m)
            #pragma unroll
            for (int r = 0; r < 4; ++r) {
                const float val = acc[m][n][r] + cb;
                acc[m][n][r] = val;
                sum[m][r] += val;
                sq[m][r] += val * val;
            }
    }
    #pragma unroll
    for (int d = 1; d < 16; d <<= 1) {
        #pragma unroll
        for (int m = 0; m < 2; ++m)
            #pragma unroll
            for (int r = 0; r < 4; ++r) {
                sum[m][r] += __shfl_xor(sum[m][r], d, 64);
                sq[m][r] += __shfl_xor(sq[m][r], d, 64);
            }
    }
    if (lw == 0) {
        #pragma unroll
        for (int m = 0; m < 2; ++m)
            #pragma unroll
            for (int r = 0; r < 4; ++r) {
                ssum[m * 16 + quad * 4 + r][wv] = sum[m][r];
                ssq[m * 16 + quad * 4 + r][wv] = sq[m][r];
            }
    }
    __syncthreads();

    float mean[2][4], rsv[2][4];
    #pragma unroll
    for (int m = 0; m < 2; ++m)
        #pragma unroll
        for (int r = 0; r < 4; ++r) {
            const int row = m * 16 + quad * 4 + r;
            const float s = ssum[row][0] + ssum[row][1] + ssum[row][2] + ssum[row][3];
            const float q = ssq[row][0] + ssq[row][1] + ssq[row][2] + ssq[row][3];
            mean[m][r] = s * (1.f / 256.f);
            const float var = q * (1.f / 256.f) - mean[m][r] * mean[m][r];
            rsv[m][r] = rsqrtf(var + 1e-5f);
        }
    #pragma unroll
    for (int n = 0; n < 4; ++n) {
        const int o = wv * 64 + n * 16 + lw;
        const float g2 = n2g[o], b2 = n2b[o];
        #pragma unroll
        for (int m = 0; m < 2; ++m)
            #pragma unroll
            for (int r = 0; r < 4; ++r) {
                const int row = m * 16 + quad * 4 + r;
                const float y = gelu_f((acc[m][n][r] - mean[m][r]) * rsv[m][r] * g2 + b2);
                ylds[row * 264 + o] = f2bf(y);
            }
    }
    __syncthreads();

    // ---- vectorized residual + store (in-place over yg is safe:
    //      all A-reads of this block's rows were consumed before barrier) ----
    #pragma unroll
    for (int jj = 0; jj < 4; ++jj) {
        const int idx = jj * 256 + tid;
        const int row = idx >> 5, seg = idx & 31;
        const size_t g = hbase + (size_t)(t0 + row) * HC + seg * 8;
        const uint4 yv = *(const uint4*)(&ylds[row * 264 + seg * 8]);
        uint4 ov;
        ov.x = addbf2(yv.x, hv[jj].x);
        ov.y = addbf2(yv.y, hv[jj].y);
        ov.z = addbf2(yv.z, hv[jj].z);
        ov.w = addbf2(yv.w, hv[jj].w);
        *(uint4*)(hout + g) = ov;
    }
}

// ---------------------------------------------------------- proj+spline ----
__global__ __launch_bounds__(256) void proj_kernel(
    const ushort* __restrict__ hin, const ushort* __restrict__ pwbf,
    const float* __restrict__ projb, const float* __restrict__ x,
    const float* __restrict__ mask, float* __restrict__ out)
{
    __shared__ __align__(16) ushort alds[64 * 264];
    __shared__ float slds[64 * 65];
    __shared__ float red[4];

    const int tid = threadIdx.x;
    const int lane = tid & 63;
    const int wv = tid >> 6;
    const int blk = blockIdx.x;
    const int b = blk >> 6;
    const int t0 = (blk & 63) << 6;
    const size_t hbase = (size_t)b * T_LEN * HC;

    #pragma unroll
    for (int jj = 0; jj < 8; ++jj) {
        const int idx = jj * 256 + tid;
        const int row = idx >> 5, seg = idx & 31;
        short8 v = *(const short8*)(hin + hbase + (size_t)(t0 + row) * HC + seg * 8);
        *(short8*)(&alds[row * 264 + seg * 8]) = v;
    }
    __syncthreads();

    const int lw = lane & 15;
    const int quad = lane >> 4;
    floatx4 acc[4];
    #pragma unroll
    for (int n = 0; n < 4; ++n) acc[n] = (floatx4){0.f, 0.f, 0.f, 0.f};
    #pragma unroll
    for (int kt = 0; kt < 8; ++kt) {
        short8 a = *(short8*)(&alds[(wv * 16 + lw) * 264 + kt * 32 + quad * 8]);
        #pragma unroll
        for (int n = 0; n < 4; ++n) {
            short8 bb = *(const short8*)(pwbf + (n * 16 + lw) * 256 + kt * 32 + quad * 8);
            acc[n] = __builtin_amdgcn_mfma_f32_16x16x32_bf16(a, bb, acc[n], 0, 0, 0);
        }
    }
    #pragma unroll
    for (int n = 0; n < 4; ++n) {
        const int o = n * 16 + lw;
        const float pb = (o < 58) ? projb[o] : 0.f;
        #pragma unroll
        for (int r = 0; r < 4; ++r) {
            const int row = wv * 16 + quad * 4 + r;
            const float mv = mask[b * T_LEN + t0 + row];
            slds[row * 65 + o] = acc[n][r] * mv + pb;
        }
    }
    __syncthreads();

    float contrib = 0.f;
    if (tid < 128) {
        const int pos = tid >> 1;
        const int ch = tid & 1;
        const int t = t0 + pos;
        float sv[29];
        #pragma unroll
        for (int j = 0; j < 29; ++j) sv[j] = slds[pos * 65 + ch * 29 + j];
        const float x1 = x[b * 16384 + (2 + ch) * 4096 + t];

        const float SC = 0.0625f;
        float cwv[11], wdv[10], chv[11], htv[10], dvv[11];
        {
            float u[10];
            float mx = -1e30f;
            #pragma unroll
            for (int j = 0; j < 10; ++j) { u[j] = sv[j] * SC; mx = fmaxf(mx, u[j]); }
            float ssm = 0.f;
            #pragma unroll
            for (int j = 0; j < 10; ++j) { u[j] = expf(u[j] - mx); ssm += u[j]; }
            const float inv = 1.f / ssm;
            float cum = 0.f;
            cwv[0] = -5.f;
            #pragma unroll
            for (int j = 0; j < 10; ++j) {
                cum += 0.001f + 0.99f * u[j] * inv;
                cwv[j + 1] = 10.f * cum - 5.f;
            }
            cwv[10] = 5.f;
            #pragma unroll
            for (int j = 0; j < 10; ++j) wdv[j] = cwv[j + 1] - cwv[j];
        }
        {
            float u[10];
            float mx = -1e30f;
            #pragma unroll
            for (int j = 0; j < 10; ++j) { u[j] = sv[10 + j] * SC; mx = fmaxf(mx, u[j]); }
            float ssm = 0.f;
            #pragma unroll
            for (int j = 0; j < 10; ++j) { u[j] = expf(u[j] - mx); ssm += u[j]; }
            const float inv = 1.f / ssm;
            float cum = 0.f;
            chv[0] = -5.f;
            #pragma unroll
            for (int j = 0; j < 10; ++j) {
                cum += 0.001f + 0.99f * u[j] * inv;
                chv[j + 1] = 10.f * cum - 5.f;
            }
            chv[10] = 5.f;
            #pragma unroll
            for (int j = 0; j < 10; ++j) htv[j] = chv[j + 1] - chv[j];
        }
        dvv[0] = 1.f;
        dvv[10] = 1.f;
        #pragma unroll
        for (int j = 1; j <= 9; ++j) dvv[j] = 0.001f + softplus_f(sv[19 + j]);

        const bool inside = (x1 >= -5.f) && (x1 <= 5.f);
        const float xc = fminf(fmaxf(x1, -5.f), 5.f);
        float in_cw = cwv[0], in_w = wdv[0], in_ch = chv[0], in_h = htv[0];
        float dk = dvv[0], dk1 = dvv[1];
        #pragma unroll
        for (int j = 1; j < 10; ++j) {
            const bool ge = (xc >= cwv[j]);
            in_cw = ge ? cwv[j] : in_cw;
            in_w  = ge ? wdv[j] : in_w;
            in_ch = ge ? chv[j] : in_ch;
            in_h  = ge ? htv[j] : in_h;
            dk    = ge ? dvv[j] : dk;
            dk1   = ge ? dvv[j + 1] : dk1;
        }
        const float th = (xc - in_cw) / in_w;
        const float t1m = th * (1.f - th);
        const float dl = in_h / in_w;
        const float num = in_h * (dl * th * th + dk * t1m);
        const float den = dl + (dk + dk1 - 2.f * dl) * t1m;
        float yv = in_ch + num / den;
        const float omt = 1.f - th;
        const float dnum = dl * dl * (dk1 * th * th + 2.f * dl * t1m + dk * omt * omt);
        float lad = logf(dnum) - 2.f * logf(den);
        if (!inside) { yv = x1; lad = 0.f; }
        const float mv = mask[b * T_LEN + t];
        out[b * 16384 + (2 + ch) * 4096 + t] = yv * mv;
        contrib = lad * mv;
    }
    #pragma unroll
    for (int d = 32; d > 0; d >>= 1) contrib += __shfl_xor(contrib, d, 64);
    if (lane == 0) red[wv] = contrib;
    __syncthreads();
    if (tid == 0) atomicAdd(out + OUT_ELEMS + b, red[0] + red[1] + red[2] + red[3]);
}

// -------------------------------------------------------------- launch ----
extern "C" void kernel_launch(void* const* d_in, const int* in_sizes, int n_in,
                              void* d_out, int out_size, void* d_ws, size_t ws_size,
                              hipStream_t stream) {
    const float* x      = (const float*)d_in[0];
    const float* mask   = (const float*)d_in[1];
    const float* pre_w  = (const float*)d_in[2];
    const float* pre_b  = (const float*)d_in[3];
    const float* sep_w  = (const float*)d_in[4];
    const float* sep_b  = (const float*)d_in[5];
    const float* conv1w = (const float*)d_in[6];
    const float* conv1b = (const float*)d_in[7];
    const float* n1g    = (const float*)d_in[8];
    const float* n1b    = (const float*)d_in[9];
    const float* n2g    = (const float*)d_in[10];
    const float* n2b    = (const float*)d_in[11];
    const float* projw  = (const float*)d_in[12];
    const float* projb  = (const float*)d_in[13];
    float* out = (float*)d_out;

    ushort* h0   = (ushort*)d_ws;
    ushort* h1   = h0 + (size_t)NPOS * HC;
    ushort* wbf  = h1 + (size_t)NPOS * HC;
    ushort* pwbf = wbf + 4 * 256 * 256;

    prep_kernel<<<1088, 256, 0, stream>>>(conv1w, projw, wbf, pwbf);
    pre_kernel<<<NPOS / 2, 256, 0, stream>>>(x, mask, pre_w, pre_b, h0, out);

    int dil = 1;
    ushort* src = h0;   // current h
    ushort* dst = h1;   // y staging, then overwritten in-place with h_next
    for (int i = 0; i < 4; ++i) {
        dwln_kernel<<<4096, 256, 0, stream>>>(src, dst,
            sep_w + i * 768, sep_b + i * 256,
            n1g + i * 256, n1b + i * 256, mask, dil);
        gemm_kernel<<<4096, 256, 0, stream>>>(dst, src, dst, wbf + i * 65536,
            conv1b + i * 256, n2g + i * 256, n2b + i * 256);
        dil *= 3;
        ushort* tmp = src; src = dst; dst = tmp;
    }
    proj_kernel<<<2048, 256, 0, stream>>>(src, pwbf, projb, x, mask, out);
}

// Round 11
// 682.448 us; speedup vs baseline: 1.0709x; 1.0709x over previous
//
#include <hip/hip_runtime.h>
#include <cmath>

typedef short short8 __attribute__((ext_vector_type(8)));
typedef float floatx4 __attribute__((ext_vector_type(4)));

#define T_LEN 4096
#define HC 256
#define NPOS (32 * 4096)
#define OUT_ELEMS (32 * 4 * 4096)

__device__ __forceinline__ ushort f2bf(float f) {
    uint u = __float_as_uint(f);
    u += 0x7FFFu + ((u >> 16) & 1u);
    return (ushort)(u >> 16);
}
__device__ __forceinline__ float bf2f(ushort u) {
    return __uint_as_float(((uint)u) << 16);
}
__device__ __forceinline__ uint addbf2(uint a, uint b) {
    const float lo = bf2f((ushort)(a & 0xffffu)) + bf2f((ushort)(b & 0xffffu));
    const float hi = bf2f((ushort)(a >> 16)) + bf2f((ushort)(b >> 16));
    return (uint)f2bf(lo) | ((uint)f2bf(hi) << 16);
}
// fast tanh-form gelu: 8 instr, no branches; |err vs exact-erf gelu| <~1.5e-3
__device__ __forceinline__ float gelu_f(float x) {
    const float x2 = x * x;
    const float w = fmaf(0.044715f * x2, x, x);
    const float e = __builtin_amdgcn_exp2f(2.3022084f * w);
    const float r = __builtin_amdgcn_rcpf(1.f + e);
    return fmaf(-x, r, x);
}
__device__ __forceinline__ float softplus_f(float x) {
    return (x > 20.f) ? x : log1pf(expf(x));
}
__device__ __forceinline__ void load8bf(const ushort* p, float m, float* o) {
    uint4 r = *(const uint4*)p;
    o[0] = bf2f((ushort)(r.x & 0xffffu)) * m;
    o[1] = bf2f((ushort)(r.x >> 16)) * m;
    o[2] = bf2f((ushort)(r.y & 0xffffu)) * m;
    o[3] = bf2f((ushort)(r.y >> 16)) * m;
    o[4] = bf2f((ushort)(r.z & 0xffffu)) * m;
    o[5] = bf2f((ushort)(r.z >> 16)) * m;
    o[6] = bf2f((ushort)(r.w & 0xffffu)) * m;
    o[7] = bf2f((ushort)(r.w >> 16)) * m;
}

// ---------------------------------------------------------------- prep ----
__global__ __launch_bounds__(256) void prep_kernel(
    const float* __restrict__ cw, const float* __restrict__ pw,
    ushort* __restrict__ wbf, ushort* __restrict__ pwbf)
{
    int idx = blockIdx.x * 256 + threadIdx.x;
    if (idx < 4 * 256 * 256) {
        wbf[idx] = f2bf(cw[idx]);
    } else if (idx < 4 * 256 * 256 + 64 * 256) {
        int j = idx - 4 * 256 * 256;
        int row = j >> 8, c = j & 255;
        pwbf[j] = (row < 58) ? f2bf(pw[row * 256 + c]) : (ushort)0;
    }
}

// ----------------------------------------------------------------- pre ----
__global__ __launch_bounds__(256) void pre_kernel(
    const float* __restrict__ x, const float* __restrict__ mask,
    const float* __restrict__ pre_w, const float* __restrict__ pre_b,
    ushort* __restrict__ h, float* __restrict__ out)
{
    const int t = threadIdx.x;
    const int p0 = blockIdx.x * 2;
    const int p = p0 + (t >> 7);
    const int o = (t & 127) * 2;
    const int b = p >> 12;
    const int tt = p & 4095;
    const float xa = x[b * 16384 + tt];
    const float xb = x[b * 16384 + 4096 + tt];
    const float4 w = *(const float4*)(pre_w + 2 * o);
    const float v0 = w.x * xa + w.y * xb + pre_b[o];
    const float v1 = w.z * xa + w.w * xb + pre_b[o + 1];
    const uint pk = (uint)f2bf(v0) | ((uint)f2bf(v1) << 16);
    *(uint*)(h + (size_t)p * HC + o) = pk;
    if (t < 4) {
        const int pp = p0 + (t >> 1);
        const int bb = pp >> 12, t2 = pp & 4095;
        const int ch = t & 1;
        out[bb * 16384 + ch * 4096 + t2] = x[bb * 16384 + ch * 4096 + t2] * mask[bb * 4096 + t2];
    }
    if (blockIdx.x == 0 && t >= 64 && t < 96) out[OUT_ELEMS + (t - 64)] = 0.f;
}

// ---------------------------------------------------------------- dwln ----
// Half-wave-per-position restructure: lanes 0-31 = pos A, lanes 32-63 =
// pos B; each lane covers 8 channels (16B loads). LN butterfly d=16..1
// stays inside each half -> ONE 5-step chain per 2 positions. 32 pos/block.
__global__ __launch_bounds__(256, 4) void dwln_kernel(
    const ushort* __restrict__ hin, ushort* __restrict__ yg,
    const float* __restrict__ sep_w, const float* __restrict__ sep_b,
    const float* __restrict__ n1g, const float* __restrict__ n1b,
    const float* __restrict__ mask, int dil)
{
    const int tid = threadIdx.x;
    const int lane = tid & 63;
    const int half = lane >> 5;
    const int ln32 = lane & 31;
    const int wv = tid >> 6;
    const int P = blockIdx.x;
    const int L = (P & 7) * 512 + (P >> 3);   // XCD-contiguous
    const int b = L >> 7;
    const int t0 = (L & 127) << 5;
    const float* maskb = mask + b * T_LEN;
    const size_t hbase = (size_t)b * T_LEN * HC;

    const int c0 = ln32 * 8;   // 8 channels per lane
    float sw[24];
    #pragma unroll
    for (int j = 0; j < 6; ++j)
        *(float4*)(sw + 4 * j) = *(const float4*)(sep_w + c0 * 3 + 4 * j);
    float sbv[8], g1v[8], b1v[8];
    *(float4*)(sbv + 0) = *(const float4*)(sep_b + c0);
    *(float4*)(sbv + 4) = *(const float4*)(sep_b + c0 + 4);
    *(float4*)(g1v + 0) = *(const float4*)(n1g + c0);
    *(float4*)(g1v + 4) = *(const float4*)(n1g + c0 + 4);
    *(float4*)(b1v + 0) = *(const float4*)(n1b + c0);
    *(float4*)(b1v + 4) = *(const float4*)(n1b + c0 + 4);

    for (int mm = 0; mm < 4; ++mm) {
        const int t = t0 + wv * 8 + mm * 2 + half;
        float hm[8] = {0, 0, 0, 0, 0, 0, 0, 0};
        float hp[8] = {0, 0, 0, 0, 0, 0, 0, 0};
        float hc[8];
        load8bf(hin + hbase + (size_t)t * HC + c0, maskb[t], hc);
        if (t >= dil)
            load8bf(hin + hbase + (size_t)(t - dil) * HC + c0, maskb[t - dil], hm);
        if (t + dil < T_LEN)
            load8bf(hin + hbase + (size_t)(t + dil) * HC + c0, maskb[t + dil], hp);
        float v[8];
        float s = 0.f, q = 0.f;
        #pragma unroll
        for (int j = 0; j < 8; ++j) {
            const float vv = sw[3 * j] * hm[j] + sw[3 * j + 1] * hc[j]
                           + sw[3 * j + 2] * hp[j] + sbv[j];
            v[j] = vv;
            s += vv;
            q += vv * vv;
        }
        #pragma unroll
        for (int d = 16; d > 0; d >>= 1) {   // stays within 32-lane half
            s += __shfl_xor(s, d, 64);
            q += __shfl_xor(q, d, 64);
        }
        const float mean = s * (1.f / 256.f);
        const float var = q * (1.f / 256.f) - mean * mean;
        const float rs = rsqrtf(var + 1e-5f);
        uint pk[4];
        #pragma unroll
        for (int j = 0; j < 4; ++j) {
            const float ya = gelu_f((v[2 * j] - mean) * rs * g1v[2 * j] + b1v[2 * j]);
            const float yb = gelu_f((v[2 * j + 1] - mean) * rs * g1v[2 * j + 1] + b1v[2 * j + 1]);
            pk[j] = (uint)f2bf(ya) | ((uint)f2bf(yb) << 16);
        }
        *(uint4*)(yg + hbase + (size_t)t * HC + c0) =
            make_uint4(pk[0], pk[1], pk[2], pk[3]);
    }
}

// ---------------------------------------------------------------- gemm ----
// (R9 exactly — best known config.) M=64 tile, grid 2048. Wave = (M-half:
// 32 rows) x (N-half: 128 outs). Direct-A from yg (L2-hot), no staging
// barrier; ylds only for the epilogue store exchange. bounds(256,3).
__global__ __launch_bounds__(256, 3) void gemm_kernel(
    const ushort* __restrict__ yg, const ushort* __restrict__ hin,
    ushort* __restrict__ hout, const ushort* __restrict__ wbf,
    const float* __restrict__ conv1_b,
    const float* __restrict__ n2g, const float* __restrict__ n2b)
{
    __shared__ __align__(16) ushort ylds[64 * 264];
    __shared__ float ssum[64][2];
    __shared__ float ssq[64][2];

    const int tid = threadIdx.x;
    const int lane = tid & 63;
    const int wv = tid >> 6;
    const int P = blockIdx.x;
    const int L = (P & 7) * 256 + (P >> 3);
    const int b = L >> 6;
    const int t0 = (L & 63) << 6;
    const size_t hbase = (size_t)b * T_LEN * HC;

    const int lw = lane & 15;
    const int quad = lane >> 4;
    const int mh = wv >> 1;
    const int nh = wv & 1;
    floatx4 acc[2][8];
    #pragma unroll
    for (int m = 0; m < 2; ++m)
        #pragma unroll
        for (int n = 0; n < 8; ++n) acc[m][n] = (floatx4){0.f, 0.f, 0.f, 0.f};

    const ushort* wb = wbf + (nh * 128 + lw) * 256 + quad * 8;
    const ushort* ya0 = yg + hbase + (size_t)(t0 + mh * 32 + lw) * HC + quad * 8;
    const ushort* ya1 = ya0 + 16 * HC;
    #pragma unroll
    for (int kt = 0; kt < 8; ++kt) {
        short8 a0 = *(const short8*)(ya0 + kt * 32);
        short8 a1 = *(const short8*)(ya1 + kt * 32);
        #pragma unroll
        for (int n = 0; n < 8; ++n) {
            short8 bb = *(const short8*)(wb + n * 4096 + kt * 32);
            acc[0][n] = __builtin_amdgcn_mfma_f32_16x16x32_bf16(a0, bb, acc[0][n], 0, 0, 0);
            acc[1][n] = __builtin_amdgcn_mfma_f32_16x16x32_bf16(a1, bb, acc[1][n], 0, 0, 0);
        }
    }

    // ---- residual prefetch: overlaps the LN epilogue below ----
    uint4 hv[8];
    #pragma unroll
    for (int jj = 0; jj < 8; ++jj) {
        const int idx = jj * 256 + tid;
        const int row = idx >> 5, seg = idx & 31;
        hv[jj] = *(const uint4*)(hin + hbase + (size_t)(t0 + row) * HC + seg * 8);
    }

    // ---- epilogue: bias + split LN(n2) over col halves ----
    float sum[2][4] = {{0, 0, 0, 0}, {0, 0, 0, 0}};
    float sq[2][4] = {{0, 0, 0, 0}, {0, 0, 0, 0}};
    #pragma unroll
    for (int n = 0; n < 8; ++n) {
        const float cb = conv1_b[nh * 128 + n * 16 + lw];
        #pragma unroll
        for (int m = 0; m < 2; ++m)
            #pragma unroll
            for (int r = 0; r < 4; ++r) {
                const float val = acc[m][n][r] + cb;
                acc[m][n][r] = val;
                sum[m][r] += val;
                sq[m][r] += val * val;
            }
    }
    #pragma unroll
    for (int d = 1; d < 16; d <<= 1) {
        #pragma unroll
        for (int m = 0; m < 2; ++m)
            #pragma unroll
            for (int r = 0; r < 4; ++r) {
                sum[m][r] += __shfl_xor(sum[m][r], d, 64);
                sq[m][r] += __shfl_xor(sq[m][r], d, 64);
            }
    }
    if (lw == 0) {
        #pragma unroll
        for (int m = 0; m < 2; ++m)
            #pragma unroll
            for (int r = 0; r < 4; ++r) {
                ssum[mh * 32 + m * 16 + quad * 4 + r][nh] = sum[m][r];
                ssq[mh * 32 + m * 16 + quad * 4 + r][nh] = sq[m][r];
            }
    }
    __syncthreads();

    float mean[2][4], rsv[2][4];
    #pragma unroll
    for (int m = 0; m < 2; ++m)
        #pragma unroll
        for (int r = 0; r < 4; ++r) {
            const int row = mh * 32 + m * 16 + quad * 4 + r;
            const float s = ssum[row][0] + ssum[row][1];
            const float q = ssq[row][0] + ssq[row][1];
            mean[m][r] = s * (1.f / 256.f);
            const float var = q * (1.f / 256.f) - mean[m][r] * mean[m][r];
            rsv[m][r] = rsqrtf(var + 1e-5f);
        }
    #pragma unroll
    for (int n = 0; n < 8; ++n) {
        const int o = nh * 128 + n * 16 + lw;
        const float g2 = n2g[o], b2 = n2b[o];
        #pragma unroll
        for (int m = 0; m < 2; ++m)
            #pragma unroll
            for (int r = 0; r < 4; ++r) {
                const int row = mh * 32 + m * 16 + quad * 4 + r;
                const float y = gelu_f((acc[m][n][r] - mean[m][r]) * rsv[m][r] * g2 + b2);
                ylds[row * 264 + o] = f2bf(y);
            }
    }
    __syncthreads();

    // ---- vectorized residual + store (in-place over yg is safe) ----
    #pragma unroll
    for (int jj = 0; jj < 8; ++jj) {
        const int idx = jj * 256 + tid;
        const int row = idx >> 5, seg = idx & 31;
        const size_t g = hbase + (size_t)(t0 + row) * HC + seg * 8;
        const uint4 yv = *(const uint4*)(&ylds[row * 264 + seg * 8]);
        uint4 ov;
        ov.x = addbf2(yv.x, hv[jj].x);
        ov.y = addbf2(yv.y, hv[jj].y);
        ov.z = addbf2(yv.z, hv[jj].z);
        ov.w = addbf2(yv.w, hv[jj].w);
        *(uint4*)(hout + g) = ov;
    }
}

// ---------------------------------------------------------- proj+spline ----
__global__ __launch_bounds__(256) void proj_kernel(
    const ushort* __restrict__ hin, const ushort* __restrict__ pwbf,
    const float* __restrict__ projb, const float* __restrict__ x,
    const float* __restrict__ mask, float* __restrict__ out)
{
    __shared__ __align__(16) ushort alds[64 * 264];
    __shared__ float slds[64 * 65];
    __shared__ float red[4];

    const int tid = threadIdx.x;
    const int lane = tid & 63;
    const int wv = tid >> 6;
    const int blk = blockIdx.x;
    const int b = blk >> 6;
    const int t0 = (blk & 63) << 6;
    const size_t hbase = (size_t)b * T_LEN * HC;

    #pragma unroll
    for (int jj = 0; jj < 8; ++jj) {
        const int idx = jj * 256 + tid;
        const int row = idx >> 5, seg = idx & 31;
        short8 v = *(const short8*)(hin + hbase + (size_t)(t0 + row) * HC + seg * 8);
        *(short8*)(&alds[row * 264 + seg * 8]) = v;
    }
    __syncthreads();

    const int lw = lane & 15;
    const int quad = lane >> 4;
    floatx4 acc[4];
    #pragma unroll
    for (int n = 0; n < 4; ++n) acc[n] = (floatx4){0.f, 0.f, 0.f, 0.f};
    #pragma unroll
    for (int kt = 0; kt < 8; ++kt) {
        short8 a = *(short8*)(&alds[(wv * 16 + lw) * 264 + kt * 32 + quad * 8]);
        #pragma unroll
        for (int n = 0; n < 4; ++n) {
            short8 bb = *(const short8*)(pwbf + (n * 16 + lw) * 256 + kt * 32 + quad * 8);
            acc[n] = __builtin_amdgcn_mfma_f32_16x16x32_bf16(a, bb, acc[n], 0, 0, 0);
        }
    }
    #pragma unroll
    for (int n = 0; n < 4; ++n) {
        const int o = n * 16 + lw;
        const float pb = (o < 58) ? projb[o] : 0.f;
        #pragma unroll
        for (int r = 0; r < 4; ++r) {
            const int row = wv * 16 + quad * 4 + r;
            const float mv = mask[b * T_LEN + t0 + row];
            slds[row * 65 + o] = acc[n][r] * mv + pb;
        }
    }
    __syncthreads();

    float contrib = 0.f;
    if (tid < 128) {
        const int pos = tid >> 1;
        const int ch = tid & 1;
        const int t = t0 + pos;
        float sv[29];
        #pragma unroll
        for (int j = 0; j < 29; ++j) sv[j] = slds[pos * 65 + ch * 29 + j];
        const float x1 = x[b * 16384 + (2 + ch) * 4096 + t];

        const float SC = 0.0625f;
        float cwv[11], wdv[10], chv[11], htv[10], dvv[11];
        {
            float u[10];
            float mx = -1e30f;
            #pragma unroll
            for (int j = 0; j < 10; ++j) { u[j] = sv[j] * SC; mx = fmaxf(mx, u[j]); }
            float ssm = 0.f;
            #pragma unroll
            for (int j = 0; j < 10; ++j) { u[j] = expf(u[j] - mx); ssm += u[j]; }
            const float inv = 1.f / ssm;
            float cum = 0.f;
            cwv[0] = -5.f;
            #pragma unroll
            for (int j = 0; j < 10; ++j) {
                cum += 0.001f + 0.99f * u[j] * inv;
                cwv[j + 1] = 10.f * cum - 5.f;
            }
            cwv[10] = 5.f;
            #pragma unroll
            for (int j = 0; j < 10; ++j) wdv[j] = cwv[j + 1] - cwv[j];
        }
        {
            float u[10];
            float mx = -1e30f;
            #pragma unroll
            for (int j = 0; j < 10; ++j) { u[j] = sv[10 + j] * SC; mx = fmaxf(mx, u[j]); }
            float ssm = 0.f;
            #pragma unroll
            for (int j = 0; j < 10; ++j) { u[j] = expf(u[j] - mx); ssm += u[j]; }
            const float inv = 1.f / ssm;
            float cum = 0.f;
            chv[0] = -5.f;
            #pragma unroll
            for (int j = 0; j < 10; ++j) {
                cum += 0.001f + 0.99f * u[j] * inv;
                chv[j + 1] = 10.f * cum - 5.f;
            }
            chv[10] = 5.f;
            #pragma unroll
            for (int j = 0; j < 10; ++j) htv[j] = chv[j + 1] - chv[j];
        }
        dvv[0] = 1.f;
        dvv[10] = 1.f;
        #pragma unroll
        for (int j = 1; j <= 9; ++j) dvv[j] = 0.001f + softplus_f(sv[19 + j]);

        const bool inside = (x1 >= -5.f) && (x1 <= 5.f);
        const float xc = fminf(fmaxf(x1, -5.f), 5.f);
        float in_cw = cwv[0], in_w = wdv[0], in_ch = chv[0], in_h = htv[0];
        float dk = dvv[0], dk1 = dvv[1];
        #pragma unroll
        for (int j = 1; j < 10; ++j) {
            const bool ge = (xc >= cwv[j]);
            in_cw = ge ? cwv[j] : in_cw;
            in_w  = ge ? wdv[j] : in_w;
            in_ch = ge ? chv[j] : in_ch;
            in_h  = ge ? htv[j] : in_h;
            dk    = ge ? dvv[j] : dk;
            dk1   = ge ? dvv[j + 1] : dk1;
        }
        const float th = (xc - in_cw) / in_w;
        const float t1m = th * (1.f - th);
        const float dl = in_h / in_w;
        const float num = in_h * (dl * th * th + dk * t1m);
        const float den = dl + (dk + dk1 - 2.f * dl) * t1m;
        float yv = in_ch + num / den;
        const float omt = 1.f - th;
        const float dnum = dl * dl * (dk1 * th * th + 2.f * dl * t1m + dk * omt * omt);
        float lad = logf(dnum) - 2.f * logf(den);
        if (!inside) { yv = x1; lad = 0.f; }
        const float mv = mask[b * T_LEN + t];
        out[b * 16384 + (2 + ch) * 4096 + t] = yv * mv;
        contrib = lad * mv;
    }
    #pragma unroll
    for (int d = 32; d > 0; d >>= 1) contrib += __shfl_xor(contrib, d, 64);
    if (lane == 0) red[wv] = contrib;
    __syncthreads();
    if (tid == 0) atomicAdd(out + OUT_ELEMS + b, red[0] + red[1] + red[2] + red[3]);
}

// -------------------------------------------------------------- launch ----
extern "C" void kernel_launch(void* const* d_in, const int* in_sizes, int n_in,
                              void* d_out, int out_size, void* d_ws, size_t ws_size,
                              hipStream_t stream) {
    const float* x      = (const float*)d_in[0];
    const float* mask   = (const float*)d_in[1];
    const float* pre_w  = (const float*)d_in[2];
    const float* pre_b  = (const float*)d_in[3];
    const float* sep_w  = (const float*)d_in[4];
    const float* sep_b  = (const float*)d_in[5];
    const float* conv1w = (const float*)d_in[6];
    const float* conv1b = (const float*)d_in[7];
    const float* n1g    = (const float*)d_in[8];
    const float* n1b    = (const float*)d_in[9];
    const float* n2g    = (const float*)d_in[10];
    const float* n2b    = (const float*)d_in[11];
    const float* projw  = (const float*)d_in[12];
    const float* projb  = (const float*)d_in[13];
    float* out = (float*)d_out;

    ushort* h0   = (ushort*)d_ws;
    ushort* h1   = h0 + (size_t)NPOS * HC;
    ushort* wbf  = h1 + (size_t)NPOS * HC;
    ushort* pwbf = wbf + 4 * 256 * 256;

    prep_kernel<<<1088, 256, 0, stream>>>(conv1w, projw, wbf, pwbf);
    pre_kernel<<<NPOS / 2, 256, 0, stream>>>(x, mask, pre_w, pre_b, h0, out);

    int dil = 1;
    ushort* src = h0;   // current h
    ushort* dst = h1;   // y staging, then overwritten in-place with h_next
    for (int i = 0; i < 4; ++i) {
        dwln_kernel<<<4096, 256, 0, stream>>>(src, dst,
            sep_w + i * 768, sep_b + i * 256,
            n1g + i * 256, n1b + i * 256, mask, dil);
        gemm_kernel<<<2048, 256, 0, stream>>>(dst, src, dst, wbf + i * 65536,
            conv1b + i * 256, n2g + i * 256, n2b + i * 256);
        dil *= 3;
        ushort* tmp = src; src = dst; dst = tmp;
    }
    proj_kernel<<<2048, 256, 0, stream>>>(src, pwbf, projb, x, mask, out);
}

// Round 12
// 676.752 us; speedup vs baseline: 1.0799x; 1.0084x over previous
//
#include <hip/hip_runtime.h>
#include <cmath>

typedef short short8 __attribute__((ext_vector_type(8)));
typedef float floatx4 __attribute__((ext_vector_type(4)));

#define T_LEN 4096
#define HC 256
#define NPOS (32 * 4096)
#define OUT_ELEMS (32 * 4 * 4096)

__device__ __forceinline__ ushort f2bf(float f) {
    uint u = __float_as_uint(f);
    u += 0x7FFFu + ((u >> 16) & 1u);
    return (ushort)(u >> 16);
}
__device__ __forceinline__ float bf2f(ushort u) {
    return __uint_as_float(((uint)u) << 16);
}
__device__ __forceinline__ uint addbf2(uint a, uint b) {
    const float lo = bf2f((ushort)(a & 0xffffu)) + bf2f((ushort)(b & 0xffffu));
    const float hi = bf2f((ushort)(a >> 16)) + bf2f((ushort)(b >> 16));
    return (uint)f2bf(lo) | ((uint)f2bf(hi) << 16);
}
// fast tanh-form gelu: 8 instr, no branches; |err vs exact-erf gelu| <~1.5e-3
__device__ __forceinline__ float gelu_f(float x) {
    const float x2 = x * x;
    const float w = fmaf(0.044715f * x2, x, x);
    const float e = __builtin_amdgcn_exp2f(2.3022084f * w);
    const float r = __builtin_amdgcn_rcpf(1.f + e);
    return fmaf(-x, r, x);
}
__device__ __forceinline__ float softplus_f(float x) {
    return (x > 20.f) ? x : log1pf(expf(x));
}
__device__ __forceinline__ void load8bf(const ushort* p, float m, float* o) {
    uint4 r = *(const uint4*)p;
    o[0] = bf2f((ushort)(r.x & 0xffffu)) * m;
    o[1] = bf2f((ushort)(r.x >> 16)) * m;
    o[2] = bf2f((ushort)(r.y & 0xffffu)) * m;
    o[3] = bf2f((ushort)(r.y >> 16)) * m;
    o[4] = bf2f((ushort)(r.z & 0xffffu)) * m;
    o[5] = bf2f((ushort)(r.z >> 16)) * m;
    o[6] = bf2f((ushort)(r.w & 0xffffu)) * m;
    o[7] = bf2f((ushort)(r.w >> 16)) * m;
}

// ---------------------------------------------------------------- prep ----
__global__ __launch_bounds__(256) void prep_kernel(
    const float* __restrict__ cw, const float* __restrict__ pw,
    ushort* __restrict__ wbf, ushort* __restrict__ pwbf)
{
    int idx = blockIdx.x * 256 + threadIdx.x;
    if (idx < 4 * 256 * 256) {
        wbf[idx] = f2bf(cw[idx]);
    } else if (idx < 4 * 256 * 256 + 64 * 256) {
        int j = idx - 4 * 256 * 256;
        int row = j >> 8, c = j & 255;
        pwbf[j] = (row < 58) ? f2bf(pw[row * 256 + c]) : (ushort)0;
    }
}

// ----------------------------------------------------------------- pre ----
__global__ __launch_bounds__(256) void pre_kernel(
    const float* __restrict__ x, const float* __restrict__ mask,
    const float* __restrict__ pre_w, const float* __restrict__ pre_b,
    ushort* __restrict__ h, float* __restrict__ out)
{
    const int t = threadIdx.x;
    const int p0 = blockIdx.x * 2;
    const int p = p0 + (t >> 7);
    const int o = (t & 127) * 2;
    const int b = p >> 12;
    const int tt = p & 4095;
    const float xa = x[b * 16384 + tt];
    const float xb = x[b * 16384 + 4096 + tt];
    const float4 w = *(const float4*)(pre_w + 2 * o);
    const float v0 = w.x * xa + w.y * xb + pre_b[o];
    const float v1 = w.z * xa + w.w * xb + pre_b[o + 1];
    const uint pk = (uint)f2bf(v0) | ((uint)f2bf(v1) << 16);
    *(uint*)(h + (size_t)p * HC + o) = pk;
    if (t < 4) {
        const int pp = p0 + (t >> 1);
        const int bb = pp >> 12, t2 = pp & 4095;
        const int ch = t & 1;
        out[bb * 16384 + ch * 4096 + t2] = x[bb * 16384 + ch * 4096 + t2] * mask[bb * 4096 + t2];
    }
    if (blockIdx.x == 0 && t >= 64 && t < 96) out[OUT_ELEMS + (t - 64)] = 0.f;
}

// ---------------------------------------------------------------- dwln ----
// (R11 — known good) Half-wave-per-position: lanes 0-31 = pos A, 32-63 =
// pos B; 8 ch/lane (16B loads); 5-step butterfly per 2 positions.
__global__ __launch_bounds__(256, 4) void dwln_kernel(
    const ushort* __restrict__ hin, ushort* __restrict__ yg,
    const float* __restrict__ sep_w, const float* __restrict__ sep_b,
    const float* __restrict__ n1g, const float* __restrict__ n1b,
    const float* __restrict__ mask, int dil)
{
    const int tid = threadIdx.x;
    const int lane = tid & 63;
    const int half = lane >> 5;
    const int ln32 = lane & 31;
    const int wv = tid >> 6;
    const int P = blockIdx.x;
    const int L = (P & 7) * 512 + (P >> 3);   // XCD-contiguous
    const int b = L >> 7;
    const int t0 = (L & 127) << 5;
    const float* maskb = mask + b * T_LEN;
    const size_t hbase = (size_t)b * T_LEN * HC;

    const int c0 = ln32 * 8;   // 8 channels per lane
    float sw[24];
    #pragma unroll
    for (int j = 0; j < 6; ++j)
        *(float4*)(sw + 4 * j) = *(const float4*)(sep_w + c0 * 3 + 4 * j);
    float sbv[8], g1v[8], b1v[8];
    *(float4*)(sbv + 0) = *(const float4*)(sep_b + c0);
    *(float4*)(sbv + 4) = *(const float4*)(sep_b + c0 + 4);
    *(float4*)(g1v + 0) = *(const float4*)(n1g + c0);
    *(float4*)(g1v + 4) = *(const float4*)(n1g + c0 + 4);
    *(float4*)(b1v + 0) = *(const float4*)(n1b + c0);
    *(float4*)(b1v + 4) = *(const float4*)(n1b + c0 + 4);

    for (int mm = 0; mm < 4; ++mm) {
        const int t = t0 + wv * 8 + mm * 2 + half;
        float hm[8] = {0, 0, 0, 0, 0, 0, 0, 0};
        float hp[8] = {0, 0, 0, 0, 0, 0, 0, 0};
        float hc[8];
        load8bf(hin + hbase + (size_t)t * HC + c0, maskb[t], hc);
        if (t >= dil)
            load8bf(hin + hbase + (size_t)(t - dil) * HC + c0, maskb[t - dil], hm);
        if (t + dil < T_LEN)
            load8bf(hin + hbase + (size_t)(t + dil) * HC + c0, maskb[t + dil], hp);
        float v[8];
        float s = 0.f, q = 0.f;
        #pragma unroll
        for (int j = 0; j < 8; ++j) {
            const float vv = sw[3 * j] * hm[j] + sw[3 * j + 1] * hc[j]
                           + sw[3 * j + 2] * hp[j] + sbv[j];
            v[j] = vv;
            s += vv;
            q += vv * vv;
        }
        #pragma unroll
        for (int d = 16; d > 0; d >>= 1) {   // stays within 32-lane half
            s += __shfl_xor(s, d, 64);
            q += __shfl_xor(q, d, 64);
        }
        const float mean = s * (1.f / 256.f);
        const float var = q * (1.f / 256.f) - mean * mean;
        const float rs = rsqrtf(var + 1e-5f);
        uint pk[4];
        #pragma unroll
        for (int j = 0; j < 4; ++j) {
            const float ya = gelu_f((v[2 * j] - mean) * rs * g1v[2 * j] + b1v[2 * j]);
            const float yb = gelu_f((v[2 * j + 1] - mean) * rs * g1v[2 * j + 1] + b1v[2 * j + 1]);
            pk[j] = (uint)f2bf(ya) | ((uint)f2bf(yb) << 16);
        }
        *(uint4*)(yg + hbase + (size_t)t * HC + c0) =
            make_uint4(pk[0], pk[1], pk[2], pk[3]);
    }
}

// ---------------------------------------------------------------- gemm ----
// R9 structure + HAND-PIPELINED K-loop: B-fragments double-buffered in
// registers (bcur/bnx, 64 VGPR) and next-kt A prefetched, so kt+1's 18
// loads are in flight during kt's 16 MFMAs — the compiler alone kept only
// ~1 kt deep (VGPR_Count 84 vs 170 cap, R7-R8 evidence).
__global__ __launch_bounds__(256, 3) void gemm_kernel(
    const ushort* __restrict__ yg, const ushort* __restrict__ hin,
    ushort* __restrict__ hout, const ushort* __restrict__ wbf,
    const float* __restrict__ conv1_b,
    const float* __restrict__ n2g, const float* __restrict__ n2b)
{
    __shared__ __align__(16) ushort ylds[64 * 264];
    __shared__ float ssum[64][2];
    __shared__ float ssq[64][2];

    const int tid = threadIdx.x;
    const int lane = tid & 63;
    const int wv = tid >> 6;
    const int P = blockIdx.x;
    const int L = (P & 7) * 256 + (P >> 3);
    const int b = L >> 6;
    const int t0 = (L & 63) << 6;
    const size_t hbase = (size_t)b * T_LEN * HC;

    const int lw = lane & 15;
    const int quad = lane >> 4;
    const int mh = wv >> 1;
    const int nh = wv & 1;
    floatx4 acc[2][8];
    #pragma unroll
    for (int m = 0; m < 2; ++m)
        #pragma unroll
        for (int n = 0; n < 8; ++n) acc[m][n] = (floatx4){0.f, 0.f, 0.f, 0.f};

    const ushort* wb = wbf + (nh * 128 + lw) * 256 + quad * 8;
    const ushort* ya0 = yg + hbase + (size_t)(t0 + mh * 32 + lw) * HC + quad * 8;
    const ushort* ya1 = ya0 + 16 * HC;

    // software pipeline: prime kt=0
    short8 a0c = *(const short8*)(ya0);
    short8 a1c = *(const short8*)(ya1);
    short8 bcur[8], bnx[8];
    #pragma unroll
    for (int n = 0; n < 8; ++n)
        bcur[n] = *(const short8*)(wb + n * 4096);

    short8 a0n, a1n;
    #pragma unroll
    for (int kt = 0; kt < 8; ++kt) {
        if (kt < 7) {
            a0n = *(const short8*)(ya0 + (kt + 1) * 32);
            a1n = *(const short8*)(ya1 + (kt + 1) * 32);
            #pragma unroll
            for (int n = 0; n < 8; ++n)
                bnx[n] = *(const short8*)(wb + n * 4096 + (kt + 1) * 32);
        }
        #pragma unroll
        for (int n = 0; n < 8; ++n) {
            acc[0][n] = __builtin_amdgcn_mfma_f32_16x16x32_bf16(a0c, bcur[n], acc[0][n], 0, 0, 0);
            acc[1][n] = __builtin_amdgcn_mfma_f32_16x16x32_bf16(a1c, bcur[n], acc[1][n], 0, 0, 0);
        }
        a0c = a0n;
        a1c = a1n;
        #pragma unroll
        for (int n = 0; n < 8; ++n) bcur[n] = bnx[n];
    }

    // ---- residual prefetch: overlaps the LN epilogue below ----
    uint4 hv[8];
    #pragma unroll
    for (int jj = 0; jj < 8; ++jj) {
        const int idx = jj * 256 + tid;
        const int row = idx >> 5, seg = idx & 31;
        hv[jj] = *(const uint4*)(hin + hbase + (size_t)(t0 + row) * HC + seg * 8);
    }

    // ---- epilogue: bias + split LN(n2) over col halves ----
    float sum[2][4] = {{0, 0, 0, 0}, {0, 0, 0, 0}};
    float sq[2][4] = {{0, 0, 0, 0}, {0, 0, 0, 0}};
    #pragma unroll
    for (int n = 0; n < 8; ++n) {
        const float cb = conv1_b[nh * 128 + n * 16 + lw];
        #pragma unroll
        for (int m = 0; m < 2; ++m)
            #pragma unroll
            for (int r = 0; r < 4; ++r) {
                const float val = acc[m][n][r] + cb;
                acc[m][n][r] = val;
                sum[m][r] += val;
                sq[m][r] += val * val;
            }
    }
    #pragma unroll
    for (int d = 1; d < 16; d <<= 1) {
        #pragma unroll
        for (int m = 0; m < 2; ++m)
            #pragma unroll
            for (int r = 0; r < 4; ++r) {
                sum[m][r] += __shfl_xor(sum[m][r], d, 64);
                sq[m][r] += __shfl_xor(sq[m][r], d, 64);
            }
    }
    if (lw == 0) {
        #pragma unroll
        for (int m = 0; m < 2; ++m)
            #pragma unroll
            for (int r = 0; r < 4; ++r) {
                ssum[mh * 32 + m * 16 + quad * 4 + r][nh] = sum[m][r];
                ssq[mh * 32 + m * 16 + quad * 4 + r][nh] = sq[m][r];
            }
    }
    __syncthreads();

    float mean[2][4], rsv[2][4];
    #pragma unroll
    for (int m = 0; m < 2; ++m)
        #pragma unroll
        for (int r = 0; r < 4; ++r) {
            const int row = mh * 32 + m * 16 + quad * 4 + r;
            const float s = ssum[row][0] + ssum[row][1];
            const float q = ssq[row][0] + ssq[row][1];
            mean[m][r] = s * (1.f / 256.f);
            const float var = q * (1.f / 256.f) - mean[m][r] * mean[m][r];
            rsv[m][r] = rsqrtf(var + 1e-5f);
        }
    #pragma unroll
    for (int n = 0; n < 8; ++n) {
        const int o = nh * 128 + n * 16 + lw;
        const float g2 = n2g[o], b2 = n2b[o];
        #pragma unroll
        for (int m = 0; m < 2; ++m)
            #pragma unroll
            for (int r = 0; r < 4; ++r) {
                const int row = mh * 32 + m * 16 + quad * 4 + r;
                const float y = gelu_f((acc[m][n][r] - mean[m][r]) * rsv[m][r] * g2 + b2);
                ylds[row * 264 + o] = f2bf(y);
            }
    }
    __syncthreads();

    // ---- vectorized residual + store (in-place over yg is safe) ----
    #pragma unroll
    for (int jj = 0; jj < 8; ++jj) {
        const int idx = jj * 256 + tid;
        const int row = idx >> 5, seg = idx & 31;
        const size_t g = hbase + (size_t)(t0 + row) * HC + seg * 8;
        const uint4 yv = *(const uint4*)(&ylds[row * 264 + seg * 8]);
        uint4 ov;
        ov.x = addbf2(yv.x, hv[jj].x);
        ov.y = addbf2(yv.y, hv[jj].y);
        ov.z = addbf2(yv.z, hv[jj].z);
        ov.w = addbf2(yv.w, hv[jj].w);
        *(uint4*)(hout + g) = ov;
    }
}

// ---------------------------------------------------------- proj+spline ----
__global__ __launch_bounds__(256) void proj_kernel(
    const ushort* __restrict__ hin, const ushort* __restrict__ pwbf,
    const float* __restrict__ projb, const float* __restrict__ x,
    const float* __restrict__ mask, float* __restrict__ out)
{
    __shared__ __align__(16) ushort alds[64 * 264];
    __shared__ float slds[64 * 65];
    __shared__ float red[4];

    const int tid = threadIdx.x;
    const int lane = tid & 63;
    const int wv = tid >> 6;
    const int blk = blockIdx.x;
    const int b = blk >> 6;
    const int t0 = (blk & 63) << 6;
    const size_t hbase = (size_t)b * T_LEN * HC;

    #pragma unroll
    for (int jj = 0; jj < 8; ++jj) {
        const int idx = jj * 256 + tid;
        const int row = idx >> 5, seg = idx & 31;
        short8 v = *(const short8*)(hin + hbase + (size_t)(t0 + row) * HC + seg * 8);
        *(short8*)(&alds[row * 264 + seg * 8]) = v;
    }
    __syncthreads();

    const int lw = lane & 15;
    const int quad = lane >> 4;
    floatx4 acc[4];
    #pragma unroll
    for (int n = 0; n < 4; ++n) acc[n] = (floatx4){0.f, 0.f, 0.f, 0.f};
    #pragma unroll
    for (int kt = 0; kt < 8; ++kt) {
        short8 a = *(short8*)(&alds[(wv * 16 + lw) * 264 + kt * 32 + quad * 8]);
        #pragma unroll
        for (int n = 0; n < 4; ++n) {
            short8 bb = *(const short8*)(pwbf + (n * 16 + lw) * 256 + kt * 32 + quad * 8);
            acc[n] = __builtin_amdgcn_mfma_f32_16x16x32_bf16(a, bb, acc[n], 0, 0, 0);
        }
    }
    #pragma unroll
    for (int n = 0; n < 4; ++n) {
        const int o = n * 16 + lw;
        const float pb = (o < 58) ? projb[o] : 0.f;
        #pragma unroll
        for (int r = 0; r < 4; ++r) {
            const int row = wv * 16 + quad * 4 + r;
            const float mv = mask[b * T_LEN + t0 + row];
            slds[row * 65 + o] = acc[n][r] * mv + pb;
        }
    }
    __syncthreads();

    float contrib = 0.f;
    if (tid < 128) {
        const int pos = tid >> 1;
        const int ch = tid & 1;
        const int t = t0 + pos;
        float sv[29];
        #pragma unroll
        for (int j = 0; j < 29; ++j) sv[j] = slds[pos * 65 + ch * 29 + j];
        const float x1 = x[b * 16384 + (2 + ch) * 4096 + t];

        const float SC = 0.0625f;
        float cwv[11], wdv[10], chv[11], htv[10], dvv[11];
        {
            float u[10];
            float mx = -1e30f;
            #pragma unroll
            for (int j = 0; j < 10; ++j) { u[j] = sv[j] * SC; mx = fmaxf(mx, u[j]); }
            float ssm = 0.f;
            #pragma unroll
            for (int j = 0; j < 10; ++j) { u[j] = expf(u[j] - mx); ssm += u[j]; }
            const float inv = 1.f / ssm;
            float cum = 0.f;
            cwv[0] = -5.f;
            #pragma unroll
            for (int j = 0; j < 10; ++j) {
                cum += 0.001f + 0.99f * u[j] * inv;
                cwv[j + 1] = 10.f * cum - 5.f;
            }
            cwv[10] = 5.f;
            #pragma unroll
            for (int j = 0; j < 10; ++j) wdv[j] = cwv[j + 1] - cwv[j];
        }
        {
            float u[10];
            float mx = -1e30f;
            #pragma unroll
            for (int j = 0; j < 10; ++j) { u[j] = sv[10 + j] * SC; mx = fmaxf(mx, u[j]); }
            float ssm = 0.f;
            #pragma unroll
            for (int j = 0; j < 10; ++j) { u[j] = expf(u[j] - mx); ssm += u[j]; }
            const float inv = 1.f / ssm;
            float cum = 0.f;
            chv[0] = -5.f;
            #pragma unroll
            for (int j = 0; j < 10; ++j) {
                cum += 0.001f + 0.99f * u[j] * inv;
                chv[j + 1] = 10.f * cum - 5.f;
            }
            chv[10] = 5.f;
            #pragma unroll
            for (int j = 0; j < 10; ++j) htv[j] = chv[j + 1] - chv[j];
        }
        dvv[0] = 1.f;
        dvv[10] = 1.f;
        #pragma unroll
        for (int j = 1; j <= 9; ++j) dvv[j] = 0.001f + softplus_f(sv[19 + j]);

        const bool inside = (x1 >= -5.f) && (x1 <= 5.f);
        const float xc = fminf(fmaxf(x1, -5.f), 5.f);
        float in_cw = cwv[0], in_w = wdv[0], in_ch = chv[0], in_h = htv[0];
        float dk = dvv[0], dk1 = dvv[1];
        #pragma unroll
        for (int j = 1; j < 10; ++j) {
            const bool ge = (xc >= cwv[j]);
            in_cw = ge ? cwv[j] : in_cw;
            in_w  = ge ? wdv[j] : in_w;
            in_ch = ge ? chv[j] : in_ch;
            in_h  = ge ? htv[j] : in_h;
            dk    = ge ? dvv[j] : dk;
            dk1   = ge ? dvv[j + 1] : dk1;
        }
        const float th = (xc - in_cw) / in_w;
        const float t1m = th * (1.f - th);
        const float dl = in_h / in_w;
        const float num = in_h * (dl * th * th + dk * t1m);
        const float den = dl + (dk + dk1 - 2.f * dl) * t1m;
        float yv = in_ch + num / den;
        const float omt = 1.f - th;
        const float dnum = dl * dl * (dk1 * th * th + 2.f * dl * t1m + dk * omt * omt);
        float lad = logf(dnum) - 2.f * logf(den);
        if (!inside) { yv = x1; lad = 0.f; }
        const float mv = mask[b * T_LEN + t];
        out[b * 16384 + (2 + ch) * 4096 + t] = yv * mv;
        contrib = lad * mv;
    }
    #pragma unroll
    for (int d = 32; d > 0; d >>= 1) contrib += __shfl_xor(contrib, d, 64);
    if (lane == 0) red[wv] = contrib;
    __syncthreads();
    if (tid == 0) atomicAdd(out + OUT_ELEMS + b, red[0] + red[1] + red[2] + red[3]);
}

// -------------------------------------------------------------- launch ----
extern "C" void kernel_launch(void* const* d_in, const int* in_sizes, int n_in,
                              void* d_out, int out_size, void* d_ws, size_t ws_size,
                              hipStream_t stream) {
    const float* x      = (const float*)d_in[0];
    const float* mask   = (const float*)d_in[1];
    const float* pre_w  = (const float*)d_in[2];
    const float* pre_b  = (const float*)d_in[3];
    const float* sep_w  = (const float*)d_in[4];
    const float* sep_b  = (const float*)d_in[5];
    const float* conv1w = (const float*)d_in[6];
    const float* conv1b = (const float*)d_in[7];
    const float* n1g    = (const float*)d_in[8];
    const float* n1b    = (const float*)d_in[9];
    const float* n2g    = (const float*)d_in[10];
    const float* n2b    = (const float*)d_in[11];
    const float* projw  = (const float*)d_in[12];
    const float* projb  = (const float*)d_in[13];
    float* out = (float*)d_out;

    ushort* h0   = (ushort*)d_ws;
    ushort* h1   = h0 + (size_t)NPOS * HC;
    ushort* wbf  = h1 + (size_t)NPOS * HC;
    ushort* pwbf = wbf + 4 * 256 * 256;

    prep_kernel<<<1088, 256, 0, stream>>>(conv1w, projw, wbf, pwbf);
    pre_kernel<<<NPOS / 2, 256, 0, stream>>>(x, mask, pre_w, pre_b, h0, out);

    int dil = 1;
    ushort* src = h0;   // current h
    ushort* dst = h1;   // y staging, then overwritten in-place with h_next
    for (int i = 0; i < 4; ++i) {
        dwln_kernel<<<4096, 256, 0, stream>>>(src, dst,
            sep_w + i * 768, sep_b + i * 256,
            n1g + i * 256, n1b + i * 256, mask, dil);
        gemm_kernel<<<2048, 256, 0, stream>>>(dst, src, dst, wbf + i * 65536,
            conv1b + i * 256, n2g + i * 256, n2b + i * 256);
        dil *= 3;
        ushort* tmp = src; src = dst; dst = tmp;
    }
    proj_kernel<<<2048, 256, 0, stream>>>(src, pwbf, projb, x, mask, out);
}

// Round 13
// 669.580 us; speedup vs baseline: 1.0915x; 1.0107x over previous
//
#include <hip/hip_runtime.h>
#include <cmath>

typedef short short8 __attribute__((ext_vector_type(8)));
typedef float floatx4 __attribute__((ext_vector_type(4)));

#define T_LEN 4096
#define HC 256
#define NPOS (32 * 4096)
#define OUT_ELEMS (32 * 4 * 4096)

__device__ __forceinline__ ushort f2bf(float f) {
    uint u = __float_as_uint(f);
    u += 0x7FFFu + ((u >> 16) & 1u);
    return (ushort)(u >> 16);
}
__device__ __forceinline__ float bf2f(ushort u) {
    return __uint_as_float(((uint)u) << 16);
}
__device__ __forceinline__ uint addbf2(uint a, uint b) {
    const float lo = bf2f((ushort)(a & 0xffffu)) + bf2f((ushort)(b & 0xffffu));
    const float hi = bf2f((ushort)(a >> 16)) + bf2f((ushort)(b >> 16));
    return (uint)f2bf(lo) | ((uint)f2bf(hi) << 16);
}
// fast tanh-form gelu: 8 instr, no branches; |err vs exact-erf gelu| <~1.5e-3
__device__ __forceinline__ float gelu_f(float x) {
    const float x2 = x * x;
    const float w = fmaf(0.044715f * x2, x, x);
    const float e = __builtin_amdgcn_exp2f(2.3022084f * w);
    const float r = __builtin_amdgcn_rcpf(1.f + e);
    return fmaf(-x, r, x);
}
__device__ __forceinline__ float softplus_f(float x) {
    return (x > 20.f) ? x : log1pf(expf(x));
}
__device__ __forceinline__ void load8bf(const ushort* p, float m, float* o) {
    uint4 r = *(const uint4*)p;
    o[0] = bf2f((ushort)(r.x & 0xffffu)) * m;
    o[1] = bf2f((ushort)(r.x >> 16)) * m;
    o[2] = bf2f((ushort)(r.y & 0xffffu)) * m;
    o[3] = bf2f((ushort)(r.y >> 16)) * m;
    o[4] = bf2f((ushort)(r.z & 0xffffu)) * m;
    o[5] = bf2f((ushort)(r.z >> 16)) * m;
    o[6] = bf2f((ushort)(r.w & 0xffffu)) * m;
    o[7] = bf2f((ushort)(r.w >> 16)) * m;
}

// ---------------------------------------------------------------- prep ----
// weights->bf16 + out x0-copy + logdet zero (absorbed from old pre_kernel)
__global__ __launch_bounds__(256) void prep_kernel(
    const float* __restrict__ cw, const float* __restrict__ pw,
    const float* __restrict__ x, const float* __restrict__ mask,
    ushort* __restrict__ wbf, ushort* __restrict__ pwbf,
    float* __restrict__ out)
{
    int idx = blockIdx.x * 256 + threadIdx.x;
    if (idx < 262144) {
        wbf[idx] = f2bf(cw[idx]);
    } else if (idx < 262144 + 16384) {
        int j = idx - 262144;
        int row = j >> 8, c = j & 255;
        pwbf[j] = (row < 58) ? f2bf(pw[row * 256 + c]) : (ushort)0;
    } else if (idx < 262144 + 16384 + 262144) {
        int j = idx - 278528;              // b, ch(0..1), t
        int b = j >> 13;
        int r = j & 8191;
        int ch = r >> 12;
        int t = r & 4095;
        out[b * 16384 + ch * 4096 + t] =
            x[b * 16384 + ch * 4096 + t] * mask[b * 4096 + t];
    } else if (idx < 262144 + 16384 + 262144 + 32) {
        out[OUT_ELEMS + (idx - 540672)] = 0.f;
    }
}

// --------------------------------------------------------------- dwln0 ----
// Layer 0 fused with pre: h = pre_w·x0 + pre_b recomputed from x (2 floats)
// instead of read from HBM; writes h0 (residual input for gemm) AND y.
// Same half-wave layout as dwln (dil=1).
__global__ __launch_bounds__(256, 4) void dwln0_kernel(
    const float* __restrict__ x, ushort* __restrict__ h0,
    ushort* __restrict__ yg,
    const float* __restrict__ pre_w, const float* __restrict__ pre_b,
    const float* __restrict__ sep_w, const float* __restrict__ sep_b,
    const float* __restrict__ n1g, const float* __restrict__ n1b,
    const float* __restrict__ mask)
{
    const int tid = threadIdx.x;
    const int lane = tid & 63;
    const int half = lane >> 5;
    const int ln32 = lane & 31;
    const int wv = tid >> 6;
    const int P = blockIdx.x;
    const int L = (P & 7) * 512 + (P >> 3);
    const int b = L >> 7;
    const int t0 = (L & 127) << 5;
    const float* maskb = mask + b * T_LEN;
    const float* xb0 = x + b * 16384;          // channel 0 of x0
    const float* xb1 = x + b * 16384 + 4096;   // channel 1 of x0
    const size_t hbase = (size_t)b * T_LEN * HC;

    const int c0 = ln32 * 8;
    float w0[8], w1[8];
    #pragma unroll
    for (int j = 0; j < 4; ++j) {
        float4 wv4 = *(const float4*)(pre_w + c0 * 2 + 4 * j);
        w0[2 * j] = wv4.x; w1[2 * j] = wv4.y;
        w0[2 * j + 1] = wv4.z; w1[2 * j + 1] = wv4.w;
    }
    float pbv[8];
    *(float4*)(pbv + 0) = *(const float4*)(pre_b + c0);
    *(float4*)(pbv + 4) = *(const float4*)(pre_b + c0 + 4);
    float sw[24];
    #pragma unroll
    for (int j = 0; j < 6; ++j)
        *(float4*)(sw + 4 * j) = *(const float4*)(sep_w + c0 * 3 + 4 * j);
    float sbv[8], g1v[8], b1v[8];
    *(float4*)(sbv + 0) = *(const float4*)(sep_b + c0);
    *(float4*)(sbv + 4) = *(const float4*)(sep_b + c0 + 4);
    *(float4*)(g1v + 0) = *(const float4*)(n1g + c0);
    *(float4*)(g1v + 4) = *(const float4*)(n1g + c0 + 4);
    *(float4*)(b1v + 0) = *(const float4*)(n1b + c0);
    *(float4*)(b1v + 4) = *(const float4*)(n1b + c0 + 4);

    for (int mm = 0; mm < 4; ++mm) {
        const int t = t0 + wv * 8 + mm * 2 + half;
        const float xa = xb0[t], xc = xb1[t];
        const float mc = maskb[t];
        float xam = 0.f, xcm = 0.f, mmk = 0.f;
        float xap = 0.f, xcp = 0.f, mpk = 0.f;
        if (t >= 1) { xam = xb0[t - 1]; xcm = xb1[t - 1]; mmk = maskb[t - 1]; }
        if (t + 1 < T_LEN) { xap = xb0[t + 1]; xcp = xb1[t + 1]; mpk = maskb[t + 1]; }

        float v[8];
        float hcv[8];
        float s = 0.f, q = 0.f;
        #pragma unroll
        for (int j = 0; j < 8; ++j) {
            const float hcj = fmaf(w0[j], xa, fmaf(w1[j], xc, pbv[j]));
            const float hmj = fmaf(w0[j], xam, fmaf(w1[j], xcm, pbv[j])) * mmk;
            const float hpj = fmaf(w0[j], xap, fmaf(w1[j], xcp, pbv[j])) * mpk;
            hcv[j] = hcj;                       // unmasked h for residual store
            const float vv = sw[3 * j] * hmj + sw[3 * j + 1] * (hcj * mc)
                           + sw[3 * j + 2] * hpj + sbv[j];
            v[j] = vv;
            s += vv;
            q += vv * vv;
        }
        #pragma unroll
        for (int d = 16; d > 0; d >>= 1) {
            s += __shfl_xor(s, d, 64);
            q += __shfl_xor(q, d, 64);
        }
        const float mean = s * (1.f / 256.f);
        const float var = q * (1.f / 256.f) - mean * mean;
        const float rs = rsqrtf(var + 1e-5f);
        uint pk[4], pkh[4];
        #pragma unroll
        for (int j = 0; j < 4; ++j) {
            const float ya = gelu_f((v[2 * j] - mean) * rs * g1v[2 * j] + b1v[2 * j]);
            const float yb = gelu_f((v[2 * j + 1] - mean) * rs * g1v[2 * j + 1] + b1v[2 * j + 1]);
            pk[j] = (uint)f2bf(ya) | ((uint)f2bf(yb) << 16);
            pkh[j] = (uint)f2bf(hcv[2 * j]) | ((uint)f2bf(hcv[2 * j + 1]) << 16);
        }
        *(uint4*)(h0 + hbase + (size_t)t * HC + c0) =
            make_uint4(pkh[0], pkh[1], pkh[2], pkh[3]);
        *(uint4*)(yg + hbase + (size_t)t * HC + c0) =
            make_uint4(pk[0], pk[1], pk[2], pk[3]);
    }
}

// ---------------------------------------------------------------- dwln ----
// (R11 — known good) Half-wave-per-position: lanes 0-31 = pos A, 32-63 =
// pos B; 8 ch/lane (16B loads); 5-step butterfly per 2 positions.
__global__ __launch_bounds__(256, 4) void dwln_kernel(
    const ushort* __restrict__ hin, ushort* __restrict__ yg,
    const float* __restrict__ sep_w, const float* __restrict__ sep_b,
    const float* __restrict__ n1g, const float* __restrict__ n1b,
    const float* __restrict__ mask, int dil)
{
    const int tid = threadIdx.x;
    const int lane = tid & 63;
    const int half = lane >> 5;
    const int ln32 = lane & 31;
    const int wv = tid >> 6;
    const int P = blockIdx.x;
    const int L = (P & 7) * 512 + (P >> 3);   // XCD-contiguous
    const int b = L >> 7;
    const int t0 = (L & 127) << 5;
    const float* maskb = mask + b * T_LEN;
    const size_t hbase = (size_t)b * T_LEN * HC;

    const int c0 = ln32 * 8;   // 8 channels per lane
    float sw[24];
    #pragma unroll
    for (int j = 0; j < 6; ++j)
        *(float4*)(sw + 4 * j) = *(const float4*)(sep_w + c0 * 3 + 4 * j);
    float sbv[8], g1v[8], b1v[8];
    *(float4*)(sbv + 0) = *(const float4*)(sep_b + c0);
    *(float4*)(sbv + 4) = *(const float4*)(sep_b + c0 + 4);
    *(float4*)(g1v + 0) = *(const float4*)(n1g + c0);
    *(float4*)(g1v + 4) = *(const float4*)(n1g + c0 + 4);
    *(float4*)(b1v + 0) = *(const float4*)(n1b + c0);
    *(float4*)(b1v + 4) = *(const float4*)(n1b + c0 + 4);

    for (int mm = 0; mm < 4; ++mm) {
        const int t = t0 + wv * 8 + mm * 2 + half;
        float hm[8] = {0, 0, 0, 0, 0, 0, 0, 0};
        float hp[8] = {0, 0, 0, 0, 0, 0, 0, 0};
        float hc[8];
        load8bf(hin + hbase + (size_t)t * HC + c0, maskb[t], hc);
        if (t >= dil)
            load8bf(hin + hbase + (size_t)(t - dil) * HC + c0, maskb[t - dil], hm);
        if (t + dil < T_LEN)
            load8bf(hin + hbase + (size_t)(t + dil) * HC + c0, maskb[t + dil], hp);
        float v[8];
        float s = 0.f, q = 0.f;
        #pragma unroll
        for (int j = 0; j < 8; ++j) {
            const float vv = sw[3 * j] * hm[j] + sw[3 * j + 1] * hc[j]
                           + sw[3 * j + 2] * hp[j] + sbv[j];
            v[j] = vv;
            s += vv;
            q += vv * vv;
        }
        #pragma unroll
        for (int d = 16; d > 0; d >>= 1) {   // stays within 32-lane half
            s += __shfl_xor(s, d, 64);
            q += __shfl_xor(q, d, 64);
        }
        const float mean = s * (1.f / 256.f);
        const float var = q * (1.f / 256.f) - mean * mean;
        const float rs = rsqrtf(var + 1e-5f);
        uint pk[4];
        #pragma unroll
        for (int j = 0; j < 4; ++j) {
            const float ya = gelu_f((v[2 * j] - mean) * rs * g1v[2 * j] + b1v[2 * j]);
            const float yb = gelu_f((v[2 * j + 1] - mean) * rs * g1v[2 * j + 1] + b1v[2 * j + 1]);
            pk[j] = (uint)f2bf(ya) | ((uint)f2bf(yb) << 16);
        }
        *(uint4*)(yg + hbase + (size_t)t * HC + c0) =
            make_uint4(pk[0], pk[1], pk[2], pk[3]);
    }
}

// ---------------------------------------------------------------- gemm ----
// (R12 — best known) R9 structure + hand-pipelined K-loop.
__global__ __launch_bounds__(256, 3) void gemm_kernel(
    const ushort* __restrict__ yg, const ushort* __restrict__ hin,
    ushort* __restrict__ hout, const ushort* __restrict__ wbf,
    const float* __restrict__ conv1_b,
    const float* __restrict__ n2g, const float* __restrict__ n2b)
{
    __shared__ __align__(16) ushort ylds[64 * 264];
    __shared__ float ssum[64][2];
    __shared__ float ssq[64][2];

    const int tid = threadIdx.x;
    const int lane = tid & 63;
    const int wv = tid >> 6;
    const int P = blockIdx.x;
    const int L = (P & 7) * 256 + (P >> 3);
    const int b = L >> 6;
    const int t0 = (L & 63) << 6;
    const size_t hbase = (size_t)b * T_LEN * HC;

    const int lw = lane & 15;
    const int quad = lane >> 4;
    const int mh = wv >> 1;
    const int nh = wv & 1;
    floatx4 acc[2][8];
    #pragma unroll
    for (int m = 0; m < 2; ++m)
        #pragma unroll
        for (int n = 0; n < 8; ++n) acc[m][n] = (floatx4){0.f, 0.f, 0.f, 0.f};

    const ushort* wb = wbf + (nh * 128 + lw) * 256 + quad * 8;
    const ushort* ya0 = yg + hbase + (size_t)(t0 + mh * 32 + lw) * HC + quad * 8;
    const ushort* ya1 = ya0 + 16 * HC;

    short8 a0c = *(const short8*)(ya0);
    short8 a1c = *(const short8*)(ya1);
    short8 bcur[8], bnx[8];
    #pragma unroll
    for (int n = 0; n < 8; ++n)
        bcur[n] = *(const short8*)(wb + n * 4096);

    short8 a0n, a1n;
    #pragma unroll
    for (int kt = 0; kt < 8; ++kt) {
        if (kt < 7) {
            a0n = *(const short8*)(ya0 + (kt + 1) * 32);
            a1n = *(const short8*)(ya1 + (kt + 1) * 32);
            #pragma unroll
            for (int n = 0; n < 8; ++n)
                bnx[n] = *(const short8*)(wb + n * 4096 + (kt + 1) * 32);
        }
        #pragma unroll
        for (int n = 0; n < 8; ++n) {
            acc[0][n] = __builtin_amdgcn_mfma_f32_16x16x32_bf16(a0c, bcur[n], acc[0][n], 0, 0, 0);
            acc[1][n] = __builtin_amdgcn_mfma_f32_16x16x32_bf16(a1c, bcur[n], acc[1][n], 0, 0, 0);
        }
        a0c = a0n;
        a1c = a1n;
        #pragma unroll
        for (int n = 0; n < 8; ++n) bcur[n] = bnx[n];
    }

    // ---- residual prefetch: overlaps the LN epilogue below ----
    uint4 hv[8];
    #pragma unroll
    for (int jj = 0; jj < 8; ++jj) {
        const int idx = jj * 256 + tid;
        const int row = idx >> 5, seg = idx & 31;
        hv[jj] = *(const uint4*)(hin + hbase + (size_t)(t0 + row) * HC + seg * 8);
    }

    // ---- epilogue: bias + split LN(n2) over col halves ----
    float sum[2][4] = {{0, 0, 0, 0}, {0, 0, 0, 0}};
    float sq[2][4] = {{0, 0, 0, 0}, {0, 0, 0, 0}};
    #pragma unroll
    for (int n = 0; n < 8; ++n) {
        const float cb = conv1_b[nh * 128 + n * 16 + lw];
        #pragma unroll
        for (int m = 0; m < 2; ++m)
            #pragma unroll
            for (int r = 0; r < 4; ++r) {
                const float val = acc[m][n][r] + cb;
                acc[m][n][r] = val;
                sum[m][r] += val;
                sq[m][r] += val * val;
            }
    }
    #pragma unroll
    for (int d = 1; d < 16; d <<= 1) {
        #pragma unroll
        for (int m = 0; m < 2; ++m)
            #pragma unroll
            for (int r = 0; r < 4; ++r) {
                sum[m][r] += __shfl_xor(sum[m][r], d, 64);
                sq[m][r] += __shfl_xor(sq[m][r], d, 64);
            }
    }
    if (lw == 0) {
        #pragma unroll
        for (int m = 0; m < 2; ++m)
            #pragma unroll
            for (int r = 0; r < 4; ++r) {
                ssum[mh * 32 + m * 16 + quad * 4 + r][nh] = sum[m][r];
                ssq[mh * 32 + m * 16 + quad * 4 + r][nh] = sq[m][r];
            }
    }
    __syncthreads();

    float mean[2][4], rsv[2][4];
    #pragma unroll
    for (int m = 0; m < 2; ++m)
        #pragma unroll
        for (int r = 0; r < 4; ++r) {
            const int row = mh * 32 + m * 16 + quad * 4 + r;
            const float s = ssum[row][0] + ssum[row][1];
            const float q = ssq[row][0] + ssq[row][1];
            mean[m][r] = s * (1.f / 256.f);
            const float var = q * (1.f / 256.f) - mean[m][r] * mean[m][r];
            rsv[m][r] = rsqrtf(var + 1e-5f);
        }
    #pragma unroll
    for (int n = 0; n < 8; ++n) {
        const int o = nh * 128 + n * 16 + lw;
        const float g2 = n2g[o], b2 = n2b[o];
        #pragma unroll
        for (int m = 0; m < 2; ++m)
            #pragma unroll
            for (int r = 0; r < 4; ++r) {
                const int row = mh * 32 + m * 16 + quad * 4 + r;
                const float y = gelu_f((acc[m][n][r] - mean[m][r]) * rsv[m][r] * g2 + b2);
                ylds[row * 264 + o] = f2bf(y);
            }
    }
    __syncthreads();

    // ---- vectorized residual + store (in-place over yg is safe) ----
    #pragma unroll
    for (int jj = 0; jj < 8; ++jj) {
        const int idx = jj * 256 + tid;
        const int row = idx >> 5, seg = idx & 31;
        const size_t g = hbase + (size_t)(t0 + row) * HC + seg * 8;
        const uint4 yv = *(const uint4*)(&ylds[row * 264 + seg * 8]);
        uint4 ov;
        ov.x = addbf2(yv.x, hv[jj].x);
        ov.y = addbf2(yv.y, hv[jj].y);
        ov.z = addbf2(yv.z, hv[jj].z);
        ov.w = addbf2(yv.w, hv[jj].w);
        *(uint4*)(hout + g) = ov;
    }
}

// ---------------------------------------------------------- proj+spline ----
__global__ __launch_bounds__(256) void proj_kernel(
    const ushort* __restrict__ hin, const ushort* __restrict__ pwbf,
    const float* __restrict__ projb, const float* __restrict__ x,
    const float* __restrict__ mask, float* __restrict__ out)
{
    __shared__ __align__(16) ushort alds[64 * 264];
    __shared__ float slds[64 * 65];
    __shared__ float red[4];

    const int tid = threadIdx.x;
    const int lane = tid & 63;
    const int wv = tid >> 6;
    const int blk = blockIdx.x;
    const int b = blk >> 6;
    const int t0 = (blk & 63) << 6;
    const size_t hbase = (size_t)b * T_LEN * HC;

    #pragma unroll
    for (int jj = 0; jj < 8; ++jj) {
        const int idx = jj * 256 + tid;
        const int row = idx >> 5, seg = idx & 31;
        short8 v = *(const short8*)(hin + hbase + (size_t)(t0 + row) * HC + seg * 8);
        *(short8*)(&alds[row * 264 + seg * 8]) = v;
    }
    __syncthreads();

    const int lw = lane & 15;
    const int quad = lane >> 4;
    floatx4 acc[4];
    #pragma unroll
    for (int n = 0; n < 4; ++n) acc[n] = (floatx4){0.f, 0.f, 0.f, 0.f};
    #pragma unroll
    for (int kt = 0; kt < 8; ++kt) {
        short8 a = *(short8*)(&alds[(wv * 16 + lw) * 264 + kt * 32 + quad * 8]);
        #pragma unroll
        for (int n = 0; n < 4; ++n) {
            short8 bb = *(const short8*)(pwbf + (n * 16 + lw) * 256 + kt * 32 + quad * 8);
            acc[n] = __builtin_amdgcn_mfma_f32_16x16x32_bf16(a, bb, acc[n], 0, 0, 0);
        }
    }
    #pragma unroll
    for (int n = 0; n < 4; ++n) {
        const int o = n * 16 + lw;
        const float pb = (o < 58) ? projb[o] : 0.f;
        #pragma unroll
        for (int r = 0; r < 4; ++r) {
            const int row = wv * 16 + quad * 4 + r;
            const float mv = mask[b * T_LEN + t0 + row];
            slds[row * 65 + o] = acc[n][r] * mv + pb;
        }
    }
    __syncthreads();

    float contrib = 0.f;
    if (tid < 128) {
        const int pos = tid >> 1;
        const int ch = tid & 1;
        const int t = t0 + pos;
        float sv[29];
        #pragma unroll
        for (int j = 0; j < 29; ++j) sv[j] = slds[pos * 65 + ch * 29 + j];
        const float x1 = x[b * 16384 + (2 + ch) * 4096 + t];

        const float SC = 0.0625f;
        float cwv[11], wdv[10], chv[11], htv[10], dvv[11];
        {
            float u[10];
            float mx = -1e30f;
            #pragma unroll
            for (int j = 0; j < 10; ++j) { u[j] = sv[j] * SC; mx = fmaxf(mx, u[j]); }
            float ssm = 0.f;
            #pragma unroll
            for (int j = 0; j < 10; ++j) { u[j] = expf(u[j] - mx); ssm += u[j]; }
            const float inv = 1.f / ssm;
            float cum = 0.f;
            cwv[0] = -5.f;
            #pragma unroll
            for (int j = 0; j < 10; ++j) {
                cum += 0.001f + 0.99f * u[j] * inv;
                cwv[j + 1] = 10.f * cum - 5.f;
            }
            cwv[10] = 5.f;
            #pragma unroll
            for (int j = 0; j < 10; ++j) wdv[j] = cwv[j + 1] - cwv[j];
        }
        {
            float u[10];
            float mx = -1e30f;
            #pragma unroll
            for (int j = 0; j < 10; ++j) { u[j] = sv[10 + j] * SC; mx = fmaxf(mx, u[j]); }
            float ssm = 0.f;
            #pragma unroll
            for (int j = 0; j < 10; ++j) { u[j] = expf(u[j] - mx); ssm += u[j]; }
            const float inv = 1.f / ssm;
            float cum = 0.f;
            chv[0] = -5.f;
            #pragma unroll
            for (int j = 0; j < 10; ++j) {
                cum += 0.001f + 0.99f * u[j] * inv;
                chv[j + 1] = 10.f * cum - 5.f;
            }
            chv[10] = 5.f;
            #pragma unroll
            for (int j = 0; j < 10; ++j) htv[j] = chv[j + 1] - chv[j];
        }
        dvv[0] = 1.f;
        dvv[10] = 1.f;
        #pragma unroll
        for (int j = 1; j <= 9; ++j) dvv[j] = 0.001f + softplus_f(sv[19 + j]);

        const bool inside = (x1 >= -5.f) && (x1 <= 5.f);
        const float xc = fminf(fmaxf(x1, -5.f), 5.f);
        float in_cw = cwv[0], in_w = wdv[0], in_ch = chv[0], in_h = htv[0];
        float dk = dvv[0], dk1 = dvv[1];
        #pragma unroll
        for (int j = 1; j < 10; ++j) {
            const bool ge = (xc >= cwv[j]);
            in_cw = ge ? cwv[j] : in_cw;
            in_w  = ge ? wdv[j] : in_w;
            in_ch = ge ? chv[j] : in_ch;
            in_h  = ge ? htv[j] : in_h;
            dk    = ge ? dvv[j] : dk;
            dk1   = ge ? dvv[j + 1] : dk1;
        }
        const float th = (xc - in_cw) / in_w;
        const float t1m = th * (1.f - th);
        const float dl = in_h / in_w;
        const float num = in_h * (dl * th * th + dk * t1m);
        const float den = dl + (dk + dk1 - 2.f * dl) * t1m;
        float yv = in_ch + num / den;
        const float omt = 1.f - th;
        const float dnum = dl * dl * (dk1 * th * th + 2.f * dl * t1m + dk * omt * omt);
        float lad = logf(dnum) - 2.f * logf(den);
        if (!inside) { yv = x1; lad = 0.f; }
        const float mv = mask[b * T_LEN + t];
        out[b * 16384 + (2 + ch) * 4096 + t] = yv * mv;
        contrib = lad * mv;
    }
    #pragma unroll
    for (int d = 32; d > 0; d >>= 1) contrib += __shfl_xor(contrib, d, 64);
    if (lane == 0) red[wv] = contrib;
    __syncthreads();
    if (tid == 0) atomicAdd(out + OUT_ELEMS + b, red[0] + red[1] + red[2] + red[3]);
}

// -------------------------------------------------------------- launch ----
extern "C" void kernel_launch(void* const* d_in, const int* in_sizes, int n_in,
                              void* d_out, int out_size, void* d_ws, size_t ws_size,
                              hipStream_t stream) {
    const float* x      = (const float*)d_in[0];
    const float* mask   = (const float*)d_in[1];
    const float* pre_w  = (const float*)d_in[2];
    const float* pre_b  = (const float*)d_in[3];
    const float* sep_w  = (const float*)d_in[4];
    const float* sep_b  = (const float*)d_in[5];
    const float* conv1w = (const float*)d_in[6];
    const float* conv1b = (const float*)d_in[7];
    const float* n1g    = (const float*)d_in[8];
    const float* n1b    = (const float*)d_in[9];
    const float* n2g    = (const float*)d_in[10];
    const float* n2b    = (const float*)d_in[11];
    const float* projw  = (const float*)d_in[12];
    const float* projb  = (const float*)d_in[13];
    float* out = (float*)d_out;

    ushort* h0   = (ushort*)d_ws;
    ushort* h1   = h0 + (size_t)NPOS * HC;
    ushort* wbf  = h1 + (size_t)NPOS * HC;
    ushort* pwbf = wbf + 4 * 256 * 256;

    prep_kernel<<<2113, 256, 0, stream>>>(conv1w, projw, x, mask, wbf, pwbf, out);

    // layer 0: fused pre + dwln (writes h0 and y=h1 in one pass)
    dwln0_kernel<<<4096, 256, 0, stream>>>(x, h0, h1,
        pre_w, pre_b, sep_w, sep_b, n1g, n1b, mask);
    gemm_kernel<<<2048, 256, 0, stream>>>(h1, h0, h1, wbf,
        conv1b, n2g, n2b);

    int dil = 3;
    ushort* src = h1;
    ushort* dst = h0;
    for (int i = 1; i < 4; ++i) {
        dwln_kernel<<<4096, 256, 0, stream>>>(src, dst,
            sep_w + i * 768, sep_b + i * 256,
            n1g + i * 256, n1b + i * 256, mask, dil);
        gemm_kernel<<<2048, 256, 0, stream>>>(dst, src, dst, wbf + i * 65536,
            conv1b + i * 256, n2g + i * 256, n2b + i * 256);
        dil *= 3;
        ushort* tmp = src; src = dst; dst = tmp;
    }
    proj_kernel<<<2048, 256, 0, stream>>>(src, pwbf, projb, x, mask, out);
}

// Round 14
// 615.183 us; speedup vs baseline: 1.1880x; 1.0884x over previous
//
#include <hip/hip_runtime.h>
#include <cmath>

typedef short short8 __attribute__((ext_vector_type(8)));
typedef float floatx4 __attribute__((ext_vector_type(4)));

#define T_LEN 4096
#define HC 256
#define NPOS (32 * 4096)
#define OUT_ELEMS (32 * 4 * 4096)

__device__ __forceinline__ ushort f2bf(float f) {
    uint u = __float_as_uint(f);
    u += 0x7FFFu + ((u >> 16) & 1u);
    return (ushort)(u >> 16);
}
__device__ __forceinline__ float bf2f(ushort u) {
    return __uint_as_float(((uint)u) << 16);
}
__device__ __forceinline__ uint addbf2(uint a, uint b) {
    const float lo = bf2f((ushort)(a & 0xffffu)) + bf2f((ushort)(b & 0xffffu));
    const float hi = bf2f((ushort)(a >> 16)) + bf2f((ushort)(b >> 16));
    return (uint)f2bf(lo) | ((uint)f2bf(hi) << 16);
}
// fast tanh-form gelu: 8 instr, no branches; |err vs exact-erf gelu| <~1.5e-3
__device__ __forceinline__ float gelu_f(float x) {
    const float x2 = x * x;
    const float w = fmaf(0.044715f * x2, x, x);
    const float e = __builtin_amdgcn_exp2f(2.3022084f * w);
    const float r = __builtin_amdgcn_rcpf(1.f + e);
    return fmaf(-x, r, x);
}
__device__ __forceinline__ float softplus_f(float x) {
    return (x > 20.f) ? x : log1pf(expf(x));
}
__device__ __forceinline__ void load8bf(const ushort* p, float m, float* o) {
    uint4 r = *(const uint4*)p;
    o[0] = bf2f((ushort)(r.x & 0xffffu)) * m;
    o[1] = bf2f((ushort)(r.x >> 16)) * m;
    o[2] = bf2f((ushort)(r.y & 0xffffu)) * m;
    o[3] = bf2f((ushort)(r.y >> 16)) * m;
    o[4] = bf2f((ushort)(r.z & 0xffffu)) * m;
    o[5] = bf2f((ushort)(r.z >> 16)) * m;
    o[6] = bf2f((ushort)(r.w & 0xffffu)) * m;
    o[7] = bf2f((ushort)(r.w >> 16)) * m;
}

// ---------------------------------------------------------------- prep ----
__global__ __launch_bounds__(256) void prep_kernel(
    const float* __restrict__ cw, const float* __restrict__ pw,
    const float* __restrict__ x, const float* __restrict__ mask,
    ushort* __restrict__ wbf, ushort* __restrict__ pwbf,
    float* __restrict__ out)
{
    int idx = blockIdx.x * 256 + threadIdx.x;
    if (idx < 262144) {
        wbf[idx] = f2bf(cw[idx]);
    } else if (idx < 262144 + 16384) {
        int j = idx - 262144;
        int row = j >> 8, c = j & 255;
        pwbf[j] = (row < 58) ? f2bf(pw[row * 256 + c]) : (ushort)0;
    } else if (idx < 262144 + 16384 + 262144) {
        int j = idx - 278528;
        int b = j >> 13;
        int r = j & 8191;
        int ch = r >> 12;
        int t = r & 4095;
        out[b * 16384 + ch * 4096 + t] =
            x[b * 16384 + ch * 4096 + t] * mask[b * 4096 + t];
    } else if (idx < 262144 + 16384 + 262144 + 32) {
        out[OUT_ELEMS + (idx - 540672)] = 0.f;
    }
}

// --------------------------------------------------------------- dwln0 ----
// (R13 — known good) Layer-0 phase 1 fused with pre: h recomputed from x.
__global__ __launch_bounds__(256, 4) void dwln0_kernel(
    const float* __restrict__ x, ushort* __restrict__ h0,
    ushort* __restrict__ yg,
    const float* __restrict__ pre_w, const float* __restrict__ pre_b,
    const float* __restrict__ sep_w, const float* __restrict__ sep_b,
    const float* __restrict__ n1g, const float* __restrict__ n1b,
    const float* __restrict__ mask)
{
    const int tid = threadIdx.x;
    const int lane = tid & 63;
    const int half = lane >> 5;
    const int ln32 = lane & 31;
    const int wv = tid >> 6;
    const int P = blockIdx.x;
    const int L = (P & 7) * 512 + (P >> 3);
    const int b = L >> 7;
    const int t0 = (L & 127) << 5;
    const float* maskb = mask + b * T_LEN;
    const float* xb0 = x + b * 16384;
    const float* xb1 = x + b * 16384 + 4096;
    const size_t hbase = (size_t)b * T_LEN * HC;

    const int c0 = ln32 * 8;
    float w0[8], w1[8];
    #pragma unroll
    for (int j = 0; j < 4; ++j) {
        float4 wv4 = *(const float4*)(pre_w + c0 * 2 + 4 * j);
        w0[2 * j] = wv4.x; w1[2 * j] = wv4.y;
        w0[2 * j + 1] = wv4.z; w1[2 * j + 1] = wv4.w;
    }
    float pbv[8];
    *(float4*)(pbv + 0) = *(const float4*)(pre_b + c0);
    *(float4*)(pbv + 4) = *(const float4*)(pre_b + c0 + 4);
    float sw[24];
    #pragma unroll
    for (int j = 0; j < 6; ++j)
        *(float4*)(sw + 4 * j) = *(const float4*)(sep_w + c0 * 3 + 4 * j);
    float sbv[8], g1v[8], b1v[8];
    *(float4*)(sbv + 0) = *(const float4*)(sep_b + c0);
    *(float4*)(sbv + 4) = *(const float4*)(sep_b + c0 + 4);
    *(float4*)(g1v + 0) = *(const float4*)(n1g + c0);
    *(float4*)(g1v + 4) = *(const float4*)(n1g + c0 + 4);
    *(float4*)(b1v + 0) = *(const float4*)(n1b + c0);
    *(float4*)(b1v + 4) = *(const float4*)(n1b + c0 + 4);

    for (int mm = 0; mm < 4; ++mm) {
        const int t = t0 + wv * 8 + mm * 2 + half;
        const float xa = xb0[t], xc = xb1[t];
        const float mc = maskb[t];
        float xam = 0.f, xcm = 0.f, mmk = 0.f;
        float xap = 0.f, xcp = 0.f, mpk = 0.f;
        if (t >= 1) { xam = xb0[t - 1]; xcm = xb1[t - 1]; mmk = maskb[t - 1]; }
        if (t + 1 < T_LEN) { xap = xb0[t + 1]; xcp = xb1[t + 1]; mpk = maskb[t + 1]; }

        float v[8];
        float hcv[8];
        float s = 0.f, q = 0.f;
        #pragma unroll
        for (int j = 0; j < 8; ++j) {
            const float hcj = fmaf(w0[j], xa, fmaf(w1[j], xc, pbv[j]));
            const float hmj = fmaf(w0[j], xam, fmaf(w1[j], xcm, pbv[j])) * mmk;
            const float hpj = fmaf(w0[j], xap, fmaf(w1[j], xcp, pbv[j])) * mpk;
            hcv[j] = hcj;
            const float vv = sw[3 * j] * hmj + sw[3 * j + 1] * (hcj * mc)
                           + sw[3 * j + 2] * hpj + sbv[j];
            v[j] = vv;
            s += vv;
            q += vv * vv;
        }
        #pragma unroll
        for (int d = 16; d > 0; d >>= 1) {
            s += __shfl_xor(s, d, 64);
            q += __shfl_xor(q, d, 64);
        }
        const float mean = s * (1.f / 256.f);
        const float var = q * (1.f / 256.f) - mean * mean;
        const float rs = rsqrtf(var + 1e-5f);
        uint pk[4], pkh[4];
        #pragma unroll
        for (int j = 0; j < 4; ++j) {
            const float ya = gelu_f((v[2 * j] - mean) * rs * g1v[2 * j] + b1v[2 * j]);
            const float yb = gelu_f((v[2 * j + 1] - mean) * rs * g1v[2 * j + 1] + b1v[2 * j + 1]);
            pk[j] = (uint)f2bf(ya) | ((uint)f2bf(yb) << 16);
            pkh[j] = (uint)f2bf(hcv[2 * j]) | ((uint)f2bf(hcv[2 * j + 1]) << 16);
        }
        *(uint4*)(h0 + hbase + (size_t)t * HC + c0) =
            make_uint4(pkh[0], pkh[1], pkh[2], pkh[3]);
        *(uint4*)(yg + hbase + (size_t)t * HC + c0) =
            make_uint4(pk[0], pk[1], pk[2], pk[3]);
    }
}

// ---------------------------------------------------------------- gemm ----
// (R12 — known good; used only for layer 0 now.)
__global__ __launch_bounds__(256, 3) void gemm_kernel(
    const ushort* __restrict__ yg, const ushort* __restrict__ hin,
    ushort* __restrict__ hout, const ushort* __restrict__ wbf,
    const float* __restrict__ conv1_b,
    const float* __restrict__ n2g, const float* __restrict__ n2b)
{
    __shared__ __align__(16) ushort ylds[64 * 264];
    __shared__ float ssum[64][2];
    __shared__ float ssq[64][2];

    const int tid = threadIdx.x;
    const int lane = tid & 63;
    const int wv = tid >> 6;
    const int P = blockIdx.x;
    const int L = (P & 7) * 256 + (P >> 3);
    const int b = L >> 6;
    const int t0 = (L & 63) << 6;
    const size_t hbase = (size_t)b * T_LEN * HC;

    const int lw = lane & 15;
    const int quad = lane >> 4;
    const int mh = wv >> 1;
    const int nh = wv & 1;
    floatx4 acc[2][8];
    #pragma unroll
    for (int m = 0; m < 2; ++m)
        #pragma unroll
        for (int n = 0; n < 8; ++n) acc[m][n] = (floatx4){0.f, 0.f, 0.f, 0.f};

    const ushort* wb = wbf + (nh * 128 + lw) * 256 + quad * 8;
    const ushort* ya0 = yg + hbase + (size_t)(t0 + mh * 32 + lw) * HC + quad * 8;
    const ushort* ya1 = ya0 + 16 * HC;

    short8 a0c = *(const short8*)(ya0);
    short8 a1c = *(const short8*)(ya1);
    short8 bcur[8], bnx[8];
    #pragma unroll
    for (int n = 0; n < 8; ++n)
        bcur[n] = *(const short8*)(wb + n * 4096);

    short8 a0n, a1n;
    #pragma unroll
    for (int kt = 0; kt < 8; ++kt) {
        if (kt < 7) {
            a0n = *(const short8*)(ya0 + (kt + 1) * 32);
            a1n = *(const short8*)(ya1 + (kt + 1) * 32);
            #pragma unroll
            for (int n = 0; n < 8; ++n)
                bnx[n] = *(const short8*)(wb + n * 4096 + (kt + 1) * 32);
        }
        #pragma unroll
        for (int n = 0; n < 8; ++n) {
            acc[0][n] = __builtin_amdgcn_mfma_f32_16x16x32_bf16(a0c, bcur[n], acc[0][n], 0, 0, 0);
            acc[1][n] = __builtin_amdgcn_mfma_f32_16x16x32_bf16(a1c, bcur[n], acc[1][n], 0, 0, 0);
        }
        a0c = a0n;
        a1c = a1n;
        #pragma unroll
        for (int n = 0; n < 8; ++n) bcur[n] = bnx[n];
    }

    uint4 hv[8];
    #pragma unroll
    for (int jj = 0; jj < 8; ++jj) {
        const int idx = jj * 256 + tid;
        const int row = idx >> 5, seg = idx & 31;
        hv[jj] = *(const uint4*)(hin + hbase + (size_t)(t0 + row) * HC + seg * 8);
    }

    float sum[2][4] = {{0, 0, 0, 0}, {0, 0, 0, 0}};
    float sq[2][4] = {{0, 0, 0, 0}, {0, 0, 0, 0}};
    #pragma unroll
    for (int n = 0; n < 8; ++n) {
        const float cb = conv1_b[nh * 128 + n * 16 + lw];
        #pragma unroll
        for (int m = 0; m < 2; ++m)
            #pragma unroll
            for (int r = 0; r < 4; ++r) {
                const float val = acc[m][n][r] + cb;
                acc[m][n][r] = val;
                sum[m][r] += val;
                sq[m][r] += val * val;
            }
    }
    #pragma unroll
    for (int d = 1; d < 16; d <<= 1) {
        #pragma unroll
        for (int m = 0; m < 2; ++m)
            #pragma unroll
            for (int r = 0; r < 4; ++r) {
                sum[m][r] += __shfl_xor(sum[m][r], d, 64);
                sq[m][r] += __shfl_xor(sq[m][r], d, 64);
            }
    }
    if (lw == 0) {
        #pragma unroll
        for (int m = 0; m < 2; ++m)
            #pragma unroll
            for (int r = 0; r < 4; ++r) {
                ssum[mh * 32 + m * 16 + quad * 4 + r][nh] = sum[m][r];
                ssq[mh * 32 + m * 16 + quad * 4 + r][nh] = sq[m][r];
            }
    }
    __syncthreads();

    float mean[2][4], rsv[2][4];
    #pragma unroll
    for (int m = 0; m < 2; ++m)
        #pragma unroll
        for (int r = 0; r < 4; ++r) {
            const int row = mh * 32 + m * 16 + quad * 4 + r;
            const float s = ssum[row][0] + ssum[row][1];
            const float q = ssq[row][0] + ssq[row][1];
            mean[m][r] = s * (1.f / 256.f);
            const float var = q * (1.f / 256.f) - mean[m][r] * mean[m][r];
            rsv[m][r] = rsqrtf(var + 1e-5f);
        }
    #pragma unroll
    for (int n = 0; n < 8; ++n) {
        const int o = nh * 128 + n * 16 + lw;
        const float g2 = n2g[o], b2 = n2b[o];
        #pragma unroll
        for (int m = 0; m < 2; ++m)
            #pragma unroll
            for (int r = 0; r < 4; ++r) {
                const int row = mh * 32 + m * 16 + quad * 4 + r;
                const float y = gelu_f((acc[m][n][r] - mean[m][r]) * rsv[m][r] * g2 + b2);
                ylds[row * 264 + o] = f2bf(y);
            }
    }
    __syncthreads();

    #pragma unroll
    for (int jj = 0; jj < 8; ++jj) {
        const int idx = jj * 256 + tid;
        const int row = idx >> 5, seg = idx & 31;
        const size_t g = hbase + (size_t)(t0 + row) * HC + seg * 8;
        const uint4 yv = *(const uint4*)(&ylds[row * 264 + seg * 8]);
        uint4 ov;
        ov.x = addbf2(yv.x, hv[jj].x);
        ov.y = addbf2(yv.y, hv[jj].y);
        ov.z = addbf2(yv.z, hv[jj].z);
        ov.w = addbf2(yv.w, hv[jj].w);
        *(uint4*)(hout + g) = ov;
    }
}

// --------------------------------------------------------------- fused ----
// Layers 1-3: dwconv(dil)+LN(n1)+gelu -> ylds (NO global y round-trip),
// barrier, R12-pipelined MFMA with A from LDS, LN(n2)+gelu+residual -> hout.
// hout != hin (ping-pong): dwconv halo reads cross blocks, in-place unsafe.
__global__ __launch_bounds__(256, 3) void fused_kernel(
    const ushort* __restrict__ hin, ushort* __restrict__ hout,
    const ushort* __restrict__ wbf,
    const float* __restrict__ sep_w, const float* __restrict__ sep_b,
    const float* __restrict__ conv1_b,
    const float* __restrict__ n1g, const float* __restrict__ n1b,
    const float* __restrict__ n2g, const float* __restrict__ n2b,
    const float* __restrict__ mask, int dil)
{
    __shared__ __align__(16) ushort ylds[64 * 264];
    __shared__ float ssum[64][2];
    __shared__ float ssq[64][2];

    const int tid = threadIdx.x;
    const int lane = tid & 63;
    const int wv = tid >> 6;
    const int P = blockIdx.x;
    const int L = (P & 7) * 256 + (P >> 3);
    const int b = L >> 6;
    const int t0 = (L & 63) << 6;
    const float* maskb = mask + b * T_LEN;
    const size_t hbase = (size_t)b * T_LEN * HC;

    // ---- phase 1: dwconv + LN(n1) + gelu -> ylds (16 rows/wave) ----
    {
        const int half = lane >> 5;
        const int ln32 = lane & 31;
        const int c0 = ln32 * 8;
        float sw[24];
        #pragma unroll
        for (int j = 0; j < 6; ++j)
            *(float4*)(sw + 4 * j) = *(const float4*)(sep_w + c0 * 3 + 4 * j);
        float sbv[8], g1v[8], b1v[8];
        *(float4*)(sbv + 0) = *(const float4*)(sep_b + c0);
        *(float4*)(sbv + 4) = *(const float4*)(sep_b + c0 + 4);
        *(float4*)(g1v + 0) = *(const float4*)(n1g + c0);
        *(float4*)(g1v + 4) = *(const float4*)(n1g + c0 + 4);
        *(float4*)(b1v + 0) = *(const float4*)(n1b + c0);
        *(float4*)(b1v + 4) = *(const float4*)(n1b + c0 + 4);

        for (int mm = 0; mm < 8; ++mm) {
            const int rloc = wv * 16 + mm * 2 + half;
            const int t = t0 + rloc;
            float hm[8] = {0, 0, 0, 0, 0, 0, 0, 0};
            float hp[8] = {0, 0, 0, 0, 0, 0, 0, 0};
            float hc[8];
            load8bf(hin + hbase + (size_t)t * HC + c0, maskb[t], hc);
            if (t >= dil)
                load8bf(hin + hbase + (size_t)(t - dil) * HC + c0, maskb[t - dil], hm);
            if (t + dil < T_LEN)
                load8bf(hin + hbase + (size_t)(t + dil) * HC + c0, maskb[t + dil], hp);
            float v[8];
            float s = 0.f, q = 0.f;
            #pragma unroll
            for (int j = 0; j < 8; ++j) {
                const float vv = sw[3 * j] * hm[j] + sw[3 * j + 1] * hc[j]
                               + sw[3 * j + 2] * hp[j] + sbv[j];
                v[j] = vv;
                s += vv;
                q += vv * vv;
            }
            #pragma unroll
            for (int d = 16; d > 0; d >>= 1) {
                s += __shfl_xor(s, d, 64);
                q += __shfl_xor(q, d, 64);
            }
            const float mean = s * (1.f / 256.f);
            const float var = q * (1.f / 256.f) - mean * mean;
            const float rs = rsqrtf(var + 1e-5f);
            uint pk[4];
            #pragma unroll
            for (int j = 0; j < 4; ++j) {
                const float ya = gelu_f((v[2 * j] - mean) * rs * g1v[2 * j] + b1v[2 * j]);
                const float yb = gelu_f((v[2 * j + 1] - mean) * rs * g1v[2 * j + 1] + b1v[2 * j + 1]);
                pk[j] = (uint)f2bf(ya) | ((uint)f2bf(yb) << 16);
            }
            *(uint4*)(&ylds[rloc * 264 + c0]) = make_uint4(pk[0], pk[1], pk[2], pk[3]);
        }
    }
    __syncthreads();

    // ---- phase 2: pipelined MFMA, A from LDS ----
    const int lw = lane & 15;
    const int quad = lane >> 4;
    const int mh = wv >> 1;
    const int nh = wv & 1;
    floatx4 acc[2][8];
    #pragma unroll
    for (int m = 0; m < 2; ++m)
        #pragma unroll
        for (int n = 0; n < 8; ++n) acc[m][n] = (floatx4){0.f, 0.f, 0.f, 0.f};

    const ushort* wb = wbf + (nh * 128 + lw) * 256 + quad * 8;
    const ushort* la0 = &ylds[(mh * 32 + lw) * 264 + quad * 8];
    const ushort* la1 = &ylds[(mh * 32 + 16 + lw) * 264 + quad * 8];

    short8 a0c = *(const short8*)(la0);
    short8 a1c = *(const short8*)(la1);
    short8 bcur[8], bnx[8];
    #pragma unroll
    for (int n = 0; n < 8; ++n)
        bcur[n] = *(const short8*)(wb + n * 4096);

    short8 a0n, a1n;
    #pragma unroll
    for (int kt = 0; kt < 8; ++kt) {
        if (kt < 7) {
            a0n = *(const short8*)(la0 + (kt + 1) * 32);
            a1n = *(const short8*)(la1 + (kt + 1) * 32);
            #pragma unroll
            for (int n = 0; n < 8; ++n)
                bnx[n] = *(const short8*)(wb + n * 4096 + (kt + 1) * 32);
        }
        #pragma unroll
        for (int n = 0; n < 8; ++n) {
            acc[0][n] = __builtin_amdgcn_mfma_f32_16x16x32_bf16(a0c, bcur[n], acc[0][n], 0, 0, 0);
            acc[1][n] = __builtin_amdgcn_mfma_f32_16x16x32_bf16(a1c, bcur[n], acc[1][n], 0, 0, 0);
        }
        a0c = a0n;
        a1c = a1n;
        #pragma unroll
        for (int n = 0; n < 8; ++n) bcur[n] = bnx[n];
    }

    // ---- residual prefetch (L2-hot: phase 1 just read these rows) ----
    uint4 hv[8];
    #pragma unroll
    for (int jj = 0; jj < 8; ++jj) {
        const int idx = jj * 256 + tid;
        const int row = idx >> 5, seg = idx & 31;
        hv[jj] = *(const uint4*)(hin + hbase + (size_t)(t0 + row) * HC + seg * 8);
    }

    // ---- epilogue: bias + split LN(n2) over col halves ----
    float sum[2][4] = {{0, 0, 0, 0}, {0, 0, 0, 0}};
    float sq[2][4] = {{0, 0, 0, 0}, {0, 0, 0, 0}};
    #pragma unroll
    for (int n = 0; n < 8; ++n) {
        const float cb = conv1_b[nh * 128 + n * 16 + lw];
        #pragma unroll
        for (int m = 0; m < 2; ++m)
            #pragma unroll
            for (int r = 0; r < 4; ++r) {
                const float val = acc[m][n][r] + cb;
                acc[m][n][r] = val;
                sum[m][r] += val;
                sq[m][r] += val * val;
            }
    }
    #pragma unroll
    for (int d = 1; d < 16; d <<= 1) {
        #pragma unroll
        for (int m = 0; m < 2; ++m)
            #pragma unroll
            for (int r = 0; r < 4; ++r) {
                sum[m][r] += __shfl_xor(sum[m][r], d, 64);
                sq[m][r] += __shfl_xor(sq[m][r], d, 64);
            }
    }
    if (lw == 0) {
        #pragma unroll
        for (int m = 0; m < 2; ++m)
            #pragma unroll
            for (int r = 0; r < 4; ++r) {
                ssum[mh * 32 + m * 16 + quad * 4 + r][nh] = sum[m][r];
                ssq[mh * 32 + m * 16 + quad * 4 + r][nh] = sq[m][r];
            }
    }
    __syncthreads();   // all K-loop ylds reads done before overwrite below

    float mean[2][4], rsv[2][4];
    #pragma unroll
    for (int m = 0; m < 2; ++m)
        #pragma unroll
        for (int r = 0; r < 4; ++r) {
            const int row = mh * 32 + m * 16 + quad * 4 + r;
            const float s = ssum[row][0] + ssum[row][1];
            const float q = ssq[row][0] + ssq[row][1];
            mean[m][r] = s * (1.f / 256.f);
            const float var = q * (1.f / 256.f) - mean[m][r] * mean[m][r];
            rsv[m][r] = rsqrtf(var + 1e-5f);
        }
    #pragma unroll
    for (int n = 0; n < 8; ++n) {
        const int o = nh * 128 + n * 16 + lw;
        const float g2 = n2g[o], b2 = n2b[o];
        #pragma unroll
        for (int m = 0; m < 2; ++m)
            #pragma unroll
            for (int r = 0; r < 4; ++r) {
                const int row = mh * 32 + m * 16 + quad * 4 + r;
                const float y = gelu_f((acc[m][n][r] - mean[m][r]) * rsv[m][r] * g2 + b2);
                ylds[row * 264 + o] = f2bf(y);
            }
    }
    __syncthreads();

    // ---- vectorized residual + store ----
    #pragma unroll
    for (int jj = 0; jj < 8; ++jj) {
        const int idx = jj * 256 + tid;
        const int row = idx >> 5, seg = idx & 31;
        const size_t g = hbase + (size_t)(t0 + row) * HC + seg * 8;
        const uint4 yv = *(const uint4*)(&ylds[row * 264 + seg * 8]);
        uint4 ov;
        ov.x = addbf2(yv.x, hv[jj].x);
        ov.y = addbf2(yv.y, hv[jj].y);
        ov.z = addbf2(yv.z, hv[jj].z);
        ov.w = addbf2(yv.w, hv[jj].w);
        *(uint4*)(hout + g) = ov;
    }
}

// ---------------------------------------------------------- proj+spline ----
__global__ __launch_bounds__(256) void proj_kernel(
    const ushort* __restrict__ hin, const ushort* __restrict__ pwbf,
    const float* __restrict__ projb, const float* __restrict__ x,
    const float* __restrict__ mask, float* __restrict__ out)
{
    __shared__ __align__(16) ushort alds[64 * 264];
    __shared__ float slds[64 * 65];
    __shared__ float red[4];

    const int tid = threadIdx.x;
    const int lane = tid & 63;
    const int wv = tid >> 6;
    const int blk = blockIdx.x;
    const int b = blk >> 6;
    const int t0 = (blk & 63) << 6;
    const size_t hbase = (size_t)b * T_LEN * HC;

    #pragma unroll
    for (int jj = 0; jj < 8; ++jj) {
        const int idx = jj * 256 + tid;
        const int row = idx >> 5, seg = idx & 31;
        short8 v = *(const short8*)(hin + hbase + (size_t)(t0 + row) * HC + seg * 8);
        *(short8*)(&alds[row * 264 + seg * 8]) = v;
    }
    __syncthreads();

    const int lw = lane & 15;
    const int quad = lane >> 4;
    floatx4 acc[4];
    #pragma unroll
    for (int n = 0; n < 4; ++n) acc[n] = (floatx4){0.f, 0.f, 0.f, 0.f};
    #pragma unroll
    for (int kt = 0; kt < 8; ++kt) {
        short8 a = *(short8*)(&alds[(wv * 16 + lw) * 264 + kt * 32 + quad * 8]);
        #pragma unroll
        for (int n = 0; n < 4; ++n) {
            short8 bb = *(const short8*)(pwbf + (n * 16 + lw) * 256 + kt * 32 + quad * 8);
            acc[n] = __builtin_amdgcn_mfma_f32_16x16x32_bf16(a, bb, acc[n], 0, 0, 0);
        }
    }
    #pragma unroll
    for (int n = 0; n < 4; ++n) {
        const int o = n * 16 + lw;
        const float pb = (o < 58) ? projb[o] : 0.f;
        #pragma unroll
        for (int r = 0; r < 4; ++r) {
            const int row = wv * 16 + quad * 4 + r;
            const float mv = mask[b * T_LEN + t0 + row];
            slds[row * 65 + o] = acc[n][r] * mv + pb;
        }
    }
    __syncthreads();

    float contrib = 0.f;
    if (tid < 128) {
        const int pos = tid >> 1;
        const int ch = tid & 1;
        const int t = t0 + pos;
        float sv[29];
        #pragma unroll
        for (int j = 0; j < 29; ++j) sv[j] = slds[pos * 65 + ch * 29 + j];
        const float x1 = x[b * 16384 + (2 + ch) * 4096 + t];

        const float SC = 0.0625f;
        float cwv[11], wdv[10], chv[11], htv[10], dvv[11];
        {
            float u[10];
            float mx = -1e30f;
            #pragma unroll
            for (int j = 0; j < 10; ++j) { u[j] = sv[j] * SC; mx = fmaxf(mx, u[j]); }
            float ssm = 0.f;
            #pragma unroll
            for (int j = 0; j < 10; ++j) { u[j] = expf(u[j] - mx); ssm += u[j]; }
            const float inv = 1.f / ssm;
            float cum = 0.f;
            cwv[0] = -5.f;
            #pragma unroll
            for (int j = 0; j < 10; ++j) {
                cum += 0.001f + 0.99f * u[j] * inv;
                cwv[j + 1] = 10.f * cum - 5.f;
            }
            cwv[10] = 5.f;
            #pragma unroll
            for (int j = 0; j < 10; ++j) wdv[j] = cwv[j + 1] - cwv[j];
        }
        {
            float u[10];
            float mx = -1e30f;
            #pragma unroll
            for (int j = 0; j < 10; ++j) { u[j] = sv[10 + j] * SC; mx = fmaxf(mx, u[j]); }
            float ssm = 0.f;
            #pragma unroll
            for (int j = 0; j < 10; ++j) { u[j] = expf(u[j] - mx); ssm += u[j]; }
            const float inv = 1.f / ssm;
            float cum = 0.f;
            chv[0] = -5.f;
            #pragma unroll
            for (int j = 0; j < 10; ++j) {
                cum += 0.001f + 0.99f * u[j] * inv;
                chv[j + 1] = 10.f * cum - 5.f;
            }
            chv[10] = 5.f;
            #pragma unroll
            for (int j = 0; j < 10; ++j) htv[j] = chv[j + 1] - chv[j];
        }
        dvv[0] = 1.f;
        dvv[10] = 1.f;
        #pragma unroll
        for (int j = 1; j <= 9; ++j) dvv[j] = 0.001f + softplus_f(sv[19 + j]);

        const bool inside = (x1 >= -5.f) && (x1 <= 5.f);
        const float xc = fminf(fmaxf(x1, -5.f), 5.f);
        float in_cw = cwv[0], in_w = wdv[0], in_ch = chv[0], in_h = htv[0];
        float dk = dvv[0], dk1 = dvv[1];
        #pragma unroll
        for (int j = 1; j < 10; ++j) {
            const bool ge = (xc >= cwv[j]);
            in_cw = ge ? cwv[j] : in_cw;
            in_w  = ge ? wdv[j] : in_w;
            in_ch = ge ? chv[j] : in_ch;
            in_h  = ge ? htv[j] : in_h;
            dk    = ge ? dvv[j] : dk;
            dk1   = ge ? dvv[j + 1] : dk1;
        }
        const float th = (xc - in_cw) / in_w;
        const float t1m = th * (1.f - th);
        const float dl = in_h / in_w;
        const float num = in_h * (dl * th * th + dk * t1m);
        const float den = dl + (dk + dk1 - 2.f * dl) * t1m;
        float yv = in_ch + num / den;
        const float omt = 1.f - th;
        const float dnum = dl * dl * (dk1 * th * th + 2.f * dl * t1m + dk * omt * omt);
        float lad = logf(dnum) - 2.f * logf(den);
        if (!inside) { yv = x1; lad = 0.f; }
        const float mv = mask[b * T_LEN + t];
        out[b * 16384 + (2 + ch) * 4096 + t] = yv * mv;
        contrib = lad * mv;
    }
    #pragma unroll
    for (int d = 32; d > 0; d >>= 1) contrib += __shfl_xor(contrib, d, 64);
    if (lane == 0) red[wv] = contrib;
    __syncthreads();
    if (tid == 0) atomicAdd(out + OUT_ELEMS + b, red[0] + red[1] + red[2] + red[3]);
}

// -------------------------------------------------------------- launch ----
extern "C" void kernel_launch(void* const* d_in, const int* in_sizes, int n_in,
                              void* d_out, int out_size, void* d_ws, size_t ws_size,
                              hipStream_t stream) {
    const float* x      = (const float*)d_in[0];
    const float* mask   = (const float*)d_in[1];
    const float* pre_w  = (const float*)d_in[2];
    const float* pre_b  = (const float*)d_in[3];
    const float* sep_w  = (const float*)d_in[4];
    const float* sep_b  = (const float*)d_in[5];
    const float* conv1w = (const float*)d_in[6];
    const float* conv1b = (const float*)d_in[7];
    const float* n1g    = (const float*)d_in[8];
    const float* n1b    = (const float*)d_in[9];
    const float* n2g    = (const float*)d_in[10];
    const float* n2b    = (const float*)d_in[11];
    const float* projw  = (const float*)d_in[12];
    const float* projb  = (const float*)d_in[13];
    float* out = (float*)d_out;

    ushort* h0   = (ushort*)d_ws;
    ushort* h1   = h0 + (size_t)NPOS * HC;
    ushort* wbf  = h1 + (size_t)NPOS * HC;
    ushort* pwbf = wbf + 4 * 256 * 256;

    prep_kernel<<<2113, 256, 0, stream>>>(conv1w, projw, x, mask, wbf, pwbf, out);

    // layer 0: fused pre + dwln (h0 = h, h1 = y), then gemm (h1 = h_next)
    dwln0_kernel<<<4096, 256, 0, stream>>>(x, h0, h1,
        pre_w, pre_b, sep_w, sep_b, n1g, n1b, mask);
    gemm_kernel<<<2048, 256, 0, stream>>>(h1, h0, h1, wbf,
        conv1b, n2g, n2b);

    // layers 1-3: fully fused (y stays in LDS); ping-pong, never in-place
    fused_kernel<<<2048, 256, 0, stream>>>(h1, h0, wbf + 1 * 65536,
        sep_w + 1 * 768, sep_b + 1 * 256, conv1b + 1 * 256,
        n1g + 1 * 256, n1b + 1 * 256, n2g + 1 * 256, n2b + 1 * 256, mask, 3);
    fused_kernel<<<2048, 256, 0, stream>>>(h0, h1, wbf + 2 * 65536,
        sep_w + 2 * 768, sep_b + 2 * 256, conv1b + 2 * 256,
        n1g + 2 * 256, n1b + 2 * 256, n2g + 2 * 256, n2b + 2 * 256, mask, 9);
    fused_kernel<<<2048, 256, 0, stream>>>(h1, h0, wbf + 3 * 65536,
        sep_w + 3 * 768, sep_b + 3 * 256, conv1b + 3 * 256,
        n1g + 3 * 256, n1b + 3 * 256, n2g + 3 * 256, n2b + 3 * 256, mask, 27);

    proj_kernel<<<2048, 256, 0, stream>>>(h0, pwbf, projb, x, mask, out);
}

// Round 15
// 573.009 us; speedup vs baseline: 1.2755x; 1.0736x over previous
//
#include <hip/hip_runtime.h>
#include <cmath>

typedef short short8 __attribute__((ext_vector_type(8)));
typedef float floatx4 __attribute__((ext_vector_type(4)));

#define T_LEN 4096
#define HC 256
#define NPOS (32 * 4096)
#define OUT_ELEMS (32 * 4 * 4096)

__device__ __forceinline__ ushort f2bf(float f) {
    uint u = __float_as_uint(f);
    u += 0x7FFFu + ((u >> 16) & 1u);
    return (ushort)(u >> 16);
}
__device__ __forceinline__ float bf2f(ushort u) {
    return __uint_as_float(((uint)u) << 16);
}
__device__ __forceinline__ uint addbf2(uint a, uint b) {
    const float lo = bf2f((ushort)(a & 0xffffu)) + bf2f((ushort)(b & 0xffffu));
    const float hi = bf2f((ushort)(a >> 16)) + bf2f((ushort)(b >> 16));
    return (uint)f2bf(lo) | ((uint)f2bf(hi) << 16);
}
// fast tanh-form gelu: 8 instr, no branches; |err vs exact-erf gelu| <~1.5e-3
__device__ __forceinline__ float gelu_f(float x) {
    const float x2 = x * x;
    const float w = fmaf(0.044715f * x2, x, x);
    const float e = __builtin_amdgcn_exp2f(2.3022084f * w);
    const float r = __builtin_amdgcn_rcpf(1.f + e);
    return fmaf(-x, r, x);
}
__device__ __forceinline__ float softplus_f(float x) {
    return (x > 20.f) ? x : log1pf(expf(x));
}
__device__ __forceinline__ void load8bf(const ushort* p, float m, float* o) {
    uint4 r = *(const uint4*)p;
    o[0] = bf2f((ushort)(r.x & 0xffffu)) * m;
    o[1] = bf2f((ushort)(r.x >> 16)) * m;
    o[2] = bf2f((ushort)(r.y & 0xffffu)) * m;
    o[3] = bf2f((ushort)(r.y >> 16)) * m;
    o[4] = bf2f((ushort)(r.z & 0xffffu)) * m;
    o[5] = bf2f((ushort)(r.z >> 16)) * m;
    o[6] = bf2f((ushort)(r.w & 0xffffu)) * m;
    o[7] = bf2f((ushort)(r.w >> 16)) * m;
}

// ---------------------------------------------------------------- prep ----
__global__ __launch_bounds__(256) void prep_kernel(
    const float* __restrict__ cw, const float* __restrict__ pw,
    const float* __restrict__ x, const float* __restrict__ mask,
    ushort* __restrict__ wbf, ushort* __restrict__ pwbf,
    float* __restrict__ out)
{
    int idx = blockIdx.x * 256 + threadIdx.x;
    if (idx < 262144) {
        wbf[idx] = f2bf(cw[idx]);
    } else if (idx < 262144 + 16384) {
        int j = idx - 262144;
        int row = j >> 8, c = j & 255;
        pwbf[j] = (row < 58) ? f2bf(pw[row * 256 + c]) : (ushort)0;
    } else if (idx < 262144 + 16384 + 262144) {
        int j = idx - 278528;
        int b = j >> 13;
        int r = j & 8191;
        int ch = r >> 12;
        int t = r & 4095;
        out[b * 16384 + ch * 4096 + t] =
            x[b * 16384 + ch * 4096 + t] * mask[b * 4096 + t];
    } else if (idx < 262144 + 16384 + 262144 + 32) {
        out[OUT_ELEMS + (idx - 540672)] = 0.f;
    }
}

// -------------------------------------------------------------- fused0 ----
// Layer 0 fully fused: phase 1 recomputes h = pre_w·x0+pre_b from x (dil=1),
// writes h (global, bf16) + y (ylds); phase 2 = R14 fused MFMA + epilogue.
// Residual hv re-read from hg: L2-hot (same block wrote it in phase 1;
// visibility via the vmcnt-draining __syncthreads).
__global__ __launch_bounds__(256, 3) void fused0_kernel(
    const float* __restrict__ x, ushort* __restrict__ hg,
    ushort* __restrict__ hout, const ushort* __restrict__ wbf,
    const float* __restrict__ pre_w, const float* __restrict__ pre_b,
    const float* __restrict__ sep_w, const float* __restrict__ sep_b,
    const float* __restrict__ conv1_b,
    const float* __restrict__ n1g, const float* __restrict__ n1b,
    const float* __restrict__ n2g, const float* __restrict__ n2b,
    const float* __restrict__ mask)
{
    __shared__ __align__(16) ushort ylds[64 * 264];
    __shared__ float ssum[64][2];
    __shared__ float ssq[64][2];

    const int tid = threadIdx.x;
    const int lane = tid & 63;
    const int wv = tid >> 6;
    const int P = blockIdx.x;
    const int L = (P & 7) * 256 + (P >> 3);
    const int b = L >> 6;
    const int t0 = (L & 63) << 6;
    const float* maskb = mask + b * T_LEN;
    const float* xb0 = x + b * 16384;
    const float* xb1 = x + b * 16384 + 4096;
    const size_t hbase = (size_t)b * T_LEN * HC;

    // ---- phase 1: h from x + dwconv(1) + LN(n1) + gelu -> ylds, h -> hg ----
    {
        const int half = lane >> 5;
        const int ln32 = lane & 31;
        const int c0 = ln32 * 8;
        float w0[8], w1[8];
        #pragma unroll
        for (int j = 0; j < 4; ++j) {
            float4 wv4 = *(const float4*)(pre_w + c0 * 2 + 4 * j);
            w0[2 * j] = wv4.x; w1[2 * j] = wv4.y;
            w0[2 * j + 1] = wv4.z; w1[2 * j + 1] = wv4.w;
        }
        float pbv[8];
        *(float4*)(pbv + 0) = *(const float4*)(pre_b + c0);
        *(float4*)(pbv + 4) = *(const float4*)(pre_b + c0 + 4);
        float sw[24];
        #pragma unroll
        for (int j = 0; j < 6; ++j)
            *(float4*)(sw + 4 * j) = *(const float4*)(sep_w + c0 * 3 + 4 * j);
        float sbv[8], g1v[8], b1v[8];
        *(float4*)(sbv + 0) = *(const float4*)(sep_b + c0);
        *(float4*)(sbv + 4) = *(const float4*)(sep_b + c0 + 4);
        *(float4*)(g1v + 0) = *(const float4*)(n1g + c0);
        *(float4*)(g1v + 4) = *(const float4*)(n1g + c0 + 4);
        *(float4*)(b1v + 0) = *(const float4*)(n1b + c0);
        *(float4*)(b1v + 4) = *(const float4*)(n1b + c0 + 4);

        for (int mm = 0; mm < 8; ++mm) {
            const int rloc = wv * 16 + mm * 2 + half;
            const int t = t0 + rloc;
            const float xa = xb0[t], xc = xb1[t];
            const float mc = maskb[t];
            float xam = 0.f, xcm = 0.f, mmk = 0.f;
            float xap = 0.f, xcp = 0.f, mpk = 0.f;
            if (t >= 1) { xam = xb0[t - 1]; xcm = xb1[t - 1]; mmk = maskb[t - 1]; }
            if (t + 1 < T_LEN) { xap = xb0[t + 1]; xcp = xb1[t + 1]; mpk = maskb[t + 1]; }

            float v[8];
            float hcv[8];
            float s = 0.f, q = 0.f;
            #pragma unroll
            for (int j = 0; j < 8; ++j) {
                const float hcj = fmaf(w0[j], xa, fmaf(w1[j], xc, pbv[j]));
                const float hmj = fmaf(w0[j], xam, fmaf(w1[j], xcm, pbv[j])) * mmk;
                const float hpj = fmaf(w0[j], xap, fmaf(w1[j], xcp, pbv[j])) * mpk;
                hcv[j] = hcj;
                const float vv = sw[3 * j] * hmj + sw[3 * j + 1] * (hcj * mc)
                               + sw[3 * j + 2] * hpj + sbv[j];
                v[j] = vv;
                s += vv;
                q += vv * vv;
            }
            #pragma unroll
            for (int d = 16; d > 0; d >>= 1) {
                s += __shfl_xor(s, d, 64);
                q += __shfl_xor(q, d, 64);
            }
            const float mean = s * (1.f / 256.f);
            const float var = q * (1.f / 256.f) - mean * mean;
            const float rs = rsqrtf(var + 1e-5f);
            uint pk[4], pkh[4];
            #pragma unroll
            for (int j = 0; j < 4; ++j) {
                const float ya = gelu_f((v[2 * j] - mean) * rs * g1v[2 * j] + b1v[2 * j]);
                const float yb = gelu_f((v[2 * j + 1] - mean) * rs * g1v[2 * j + 1] + b1v[2 * j + 1]);
                pk[j] = (uint)f2bf(ya) | ((uint)f2bf(yb) << 16);
                pkh[j] = (uint)f2bf(hcv[2 * j]) | ((uint)f2bf(hcv[2 * j + 1]) << 16);
            }
            *(uint4*)(&ylds[rloc * 264 + c0]) = make_uint4(pk[0], pk[1], pk[2], pk[3]);
            *(uint4*)(hg + hbase + (size_t)t * HC + c0) =
                make_uint4(pkh[0], pkh[1], pkh[2], pkh[3]);
        }
    }
    __syncthreads();

    // ---- phase 2: pipelined MFMA, A from LDS (R14 fused, verbatim) ----
    const int lw = lane & 15;
    const int quad = lane >> 4;
    const int mh = wv >> 1;
    const int nh = wv & 1;
    floatx4 acc[2][8];
    #pragma unroll
    for (int m = 0; m < 2; ++m)
        #pragma unroll
        for (int n = 0; n < 8; ++n) acc[m][n] = (floatx4){0.f, 0.f, 0.f, 0.f};

    const ushort* wb = wbf + (nh * 128 + lw) * 256 + quad * 8;
    const ushort* la0 = &ylds[(mh * 32 + lw) * 264 + quad * 8];
    const ushort* la1 = &ylds[(mh * 32 + 16 + lw) * 264 + quad * 8];

    short8 a0c = *(const short8*)(la0);
    short8 a1c = *(const short8*)(la1);
    short8 bcur[8], bnx[8];
    #pragma unroll
    for (int n = 0; n < 8; ++n)
        bcur[n] = *(const short8*)(wb + n * 4096);

    short8 a0n, a1n;
    #pragma unroll
    for (int kt = 0; kt < 8; ++kt) {
        if (kt < 7) {
            a0n = *(const short8*)(la0 + (kt + 1) * 32);
            a1n = *(const short8*)(la1 + (kt + 1) * 32);
            #pragma unroll
            for (int n = 0; n < 8; ++n)
                bnx[n] = *(const short8*)(wb + n * 4096 + (kt + 1) * 32);
        }
        #pragma unroll
        for (int n = 0; n < 8; ++n) {
            acc[0][n] = __builtin_amdgcn_mfma_f32_16x16x32_bf16(a0c, bcur[n], acc[0][n], 0, 0, 0);
            acc[1][n] = __builtin_amdgcn_mfma_f32_16x16x32_bf16(a1c, bcur[n], acc[1][n], 0, 0, 0);
        }
        a0c = a0n;
        a1c = a1n;
        #pragma unroll
        for (int n = 0; n < 8; ++n) bcur[n] = bnx[n];
    }

    uint4 hv[8];
    #pragma unroll
    for (int jj = 0; jj < 8; ++jj) {
        const int idx = jj * 256 + tid;
        const int row = idx >> 5, seg = idx & 31;
        hv[jj] = *(const uint4*)(hg + hbase + (size_t)(t0 + row) * HC + seg * 8);
    }

    float sum[2][4] = {{0, 0, 0, 0}, {0, 0, 0, 0}};
    float sq[2][4] = {{0, 0, 0, 0}, {0, 0, 0, 0}};
    #pragma unroll
    for (int n = 0; n < 8; ++n) {
        const float cb = conv1_b[nh * 128 + n * 16 + lw];
        #pragma unroll
        for (int m = 0; m < 2; ++m)
            #pragma unroll
            for (int r = 0; r < 4; ++r) {
                const float val = acc[m][n][r] + cb;
                acc[m][n][r] = val;
                sum[m][r] += val;
                sq[m][r] += val * val;
            }
    }
    #pragma unroll
    for (int d = 1; d < 16; d <<= 1) {
        #pragma unroll
        for (int m = 0; m < 2; ++m)
            #pragma unroll
            for (int r = 0; r < 4; ++r) {
                sum[m][r] += __shfl_xor(sum[m][r], d, 64);
                sq[m][r] += __shfl_xor(sq[m][r], d, 64);
            }
    }
    if (lw == 0) {
        #pragma unroll
        for (int m = 0; m < 2; ++m)
            #pragma unroll
            for (int r = 0; r < 4; ++r) {
                ssum[mh * 32 + m * 16 + quad * 4 + r][nh] = sum[m][r];
                ssq[mh * 32 + m * 16 + quad * 4 + r][nh] = sq[m][r];
            }
    }
    __syncthreads();

    float mean[2][4], rsv[2][4];
    #pragma unroll
    for (int m = 0; m < 2; ++m)
        #pragma unroll
        for (int r = 0; r < 4; ++r) {
            const int row = mh * 32 + m * 16 + quad * 4 + r;
            const float s = ssum[row][0] + ssum[row][1];
            const float q = ssq[row][0] + ssq[row][1];
            mean[m][r] = s * (1.f / 256.f);
            const float var = q * (1.f / 256.f) - mean[m][r] * mean[m][r];
            rsv[m][r] = rsqrtf(var + 1e-5f);
        }
    #pragma unroll
    for (int n = 0; n < 8; ++n) {
        const int o = nh * 128 + n * 16 + lw;
        const float g2 = n2g[o], b2 = n2b[o];
        #pragma unroll
        for (int m = 0; m < 2; ++m)
            #pragma unroll
            for (int r = 0; r < 4; ++r) {
                const int row = mh * 32 + m * 16 + quad * 4 + r;
                const float y = gelu_f((acc[m][n][r] - mean[m][r]) * rsv[m][r] * g2 + b2);
                ylds[row * 264 + o] = f2bf(y);
            }
    }
    __syncthreads();

    #pragma unroll
    for (int jj = 0; jj < 8; ++jj) {
        const int idx = jj * 256 + tid;
        const int row = idx >> 5, seg = idx & 31;
        const size_t g = hbase + (size_t)(t0 + row) * HC + seg * 8;
        const uint4 yv = *(const uint4*)(&ylds[row * 264 + seg * 8]);
        uint4 ov;
        ov.x = addbf2(yv.x, hv[jj].x);
        ov.y = addbf2(yv.y, hv[jj].y);
        ov.z = addbf2(yv.z, hv[jj].z);
        ov.w = addbf2(yv.w, hv[jj].w);
        *(uint4*)(hout + g) = ov;
    }
}

// --------------------------------------------------------------- fused ----
// (R14 — known good) Layers 1-3: dwconv+LN+gelu -> ylds, pipelined MFMA,
// LN(n2)+gelu+residual -> hout. Ping-pong, never in-place.
__global__ __launch_bounds__(256, 3) void fused_kernel(
    const ushort* __restrict__ hin, ushort* __restrict__ hout,
    const ushort* __restrict__ wbf,
    const float* __restrict__ sep_w, const float* __restrict__ sep_b,
    const float* __restrict__ conv1_b,
    const float* __restrict__ n1g, const float* __restrict__ n1b,
    const float* __restrict__ n2g, const float* __restrict__ n2b,
    const float* __restrict__ mask, int dil)
{
    __shared__ __align__(16) ushort ylds[64 * 264];
    __shared__ float ssum[64][2];
    __shared__ float ssq[64][2];

    const int tid = threadIdx.x;
    const int lane = tid & 63;
    const int wv = tid >> 6;
    const int P = blockIdx.x;
    const int L = (P & 7) * 256 + (P >> 3);
    const int b = L >> 6;
    const int t0 = (L & 63) << 6;
    const float* maskb = mask + b * T_LEN;
    const size_t hbase = (size_t)b * T_LEN * HC;

    {
        const int half = lane >> 5;
        const int ln32 = lane & 31;
        const int c0 = ln32 * 8;
        float sw[24];
        #pragma unroll
        for (int j = 0; j < 6; ++j)
            *(float4*)(sw + 4 * j) = *(const float4*)(sep_w + c0 * 3 + 4 * j);
        float sbv[8], g1v[8], b1v[8];
        *(float4*)(sbv + 0) = *(const float4*)(sep_b + c0);
        *(float4*)(sbv + 4) = *(const float4*)(sep_b + c0 + 4);
        *(float4*)(g1v + 0) = *(const float4*)(n1g + c0);
        *(float4*)(g1v + 4) = *(const float4*)(n1g + c0 + 4);
        *(float4*)(b1v + 0) = *(const float4*)(n1b + c0);
        *(float4*)(b1v + 4) = *(const float4*)(n1b + c0 + 4);

        for (int mm = 0; mm < 8; ++mm) {
            const int rloc = wv * 16 + mm * 2 + half;
            const int t = t0 + rloc;
            float hm[8] = {0, 0, 0, 0, 0, 0, 0, 0};
            float hp[8] = {0, 0, 0, 0, 0, 0, 0, 0};
            float hc[8];
            load8bf(hin + hbase + (size_t)t * HC + c0, maskb[t], hc);
            if (t >= dil)
                load8bf(hin + hbase + (size_t)(t - dil) * HC + c0, maskb[t - dil], hm);
            if (t + dil < T_LEN)
                load8bf(hin + hbase + (size_t)(t + dil) * HC + c0, maskb[t + dil], hp);
            float v[8];
            float s = 0.f, q = 0.f;
            #pragma unroll
            for (int j = 0; j < 8; ++j) {
                const float vv = sw[3 * j] * hm[j] + sw[3 * j + 1] * hc[j]
                               + sw[3 * j + 2] * hp[j] + sbv[j];
                v[j] = vv;
                s += vv;
                q += vv * vv;
            }
            #pragma unroll
            for (int d = 16; d > 0; d >>= 1) {
                s += __shfl_xor(s, d, 64);
                q += __shfl_xor(q, d, 64);
            }
            const float mean = s * (1.f / 256.f);
            const float var = q * (1.f / 256.f) - mean * mean;
            const float rs = rsqrtf(var + 1e-5f);
            uint pk[4];
            #pragma unroll
            for (int j = 0; j < 4; ++j) {
                const float ya = gelu_f((v[2 * j] - mean) * rs * g1v[2 * j] + b1v[2 * j]);
                const float yb = gelu_f((v[2 * j + 1] - mean) * rs * g1v[2 * j + 1] + b1v[2 * j + 1]);
                pk[j] = (uint)f2bf(ya) | ((uint)f2bf(yb) << 16);
            }
            *(uint4*)(&ylds[rloc * 264 + c0]) = make_uint4(pk[0], pk[1], pk[2], pk[3]);
        }
    }
    __syncthreads();

    const int lw = lane & 15;
    const int quad = lane >> 4;
    const int mh = wv >> 1;
    const int nh = wv & 1;
    floatx4 acc[2][8];
    #pragma unroll
    for (int m = 0; m < 2; ++m)
        #pragma unroll
        for (int n = 0; n < 8; ++n) acc[m][n] = (floatx4){0.f, 0.f, 0.f, 0.f};

    const ushort* wb = wbf + (nh * 128 + lw) * 256 + quad * 8;
    const ushort* la0 = &ylds[(mh * 32 + lw) * 264 + quad * 8];
    const ushort* la1 = &ylds[(mh * 32 + 16 + lw) * 264 + quad * 8];

    short8 a0c = *(const short8*)(la0);
    short8 a1c = *(const short8*)(la1);
    short8 bcur[8], bnx[8];
    #pragma unroll
    for (int n = 0; n < 8; ++n)
        bcur[n] = *(const short8*)(wb + n * 4096);

    short8 a0n, a1n;
    #pragma unroll
    for (int kt = 0; kt < 8; ++kt) {
        if (kt < 7) {
            a0n = *(const short8*)(la0 + (kt + 1) * 32);
            a1n = *(const short8*)(la1 + (kt + 1) * 32);
            #pragma unroll
            for (int n = 0; n < 8; ++n)
                bnx[n] = *(const short8*)(wb + n * 4096 + (kt + 1) * 32);
        }
        #pragma unroll
        for (int n = 0; n < 8; ++n) {
            acc[0][n] = __builtin_amdgcn_mfma_f32_16x16x32_bf16(a0c, bcur[n], acc[0][n], 0, 0, 0);
            acc[1][n] = __builtin_amdgcn_mfma_f32_16x16x32_bf16(a1c, bcur[n], acc[1][n], 0, 0, 0);
        }
        a0c = a0n;
        a1c = a1n;
        #pragma unroll
        for (int n = 0; n < 8; ++n) bcur[n] = bnx[n];
    }

    uint4 hv[8];
    #pragma unroll
    for (int jj = 0; jj < 8; ++jj) {
        const int idx = jj * 256 + tid;
        const int row = idx >> 5, seg = idx & 31;
        hv[jj] = *(const uint4*)(hin + hbase + (size_t)(t0 + row) * HC + seg * 8);
    }

    float sum[2][4] = {{0, 0, 0, 0}, {0, 0, 0, 0}};
    float sq[2][4] = {{0, 0, 0, 0}, {0, 0, 0, 0}};
    #pragma unroll
    for (int n = 0; n < 8; ++n) {
        const float cb = conv1_b[nh * 128 + n * 16 + lw];
        #pragma unroll
        for (int m = 0; m < 2; ++m)
            #pragma unroll
            for (int r = 0; r < 4; ++r) {
                const float val = acc[m][n][r] + cb;
                acc[m][n][r] = val;
                sum[m][r] += val;
                sq[m][r] += val * val;
            }
    }
    #pragma unroll
    for (int d = 1; d < 16; d <<= 1) {
        #pragma unroll
        for (int m = 0; m < 2; ++m)
            #pragma unroll
            for (int r = 0; r < 4; ++r) {
                sum[m][r] += __shfl_xor(sum[m][r], d, 64);
                sq[m][r] += __shfl_xor(sq[m][r], d, 64);
            }
    }
    if (lw == 0) {
        #pragma unroll
        for (int m = 0; m < 2; ++m)
            #pragma unroll
            for (int r = 0; r < 4; ++r) {
                ssum[mh * 32 + m * 16 + quad * 4 + r][nh] = sum[m][r];
                ssq[mh * 32 + m * 16 + quad * 4 + r][nh] = sq[m][r];
            }
    }
    __syncthreads();

    float mean[2][4], rsv[2][4];
    #pragma unroll
    for (int m = 0; m < 2; ++m)
        #pragma unroll
        for (int r = 0; r < 4; ++r) {
            const int row = mh * 32 + m * 16 + quad * 4 + r;
            const float s = ssum[row][0] + ssum[row][1];
            const float q = ssq[row][0] + ssq[row][1];
            mean[m][r] = s * (1.f / 256.f);
            const float var = q * (1.f / 256.f) - mean[m][r] * mean[m][r];
            rsv[m][r] = rsqrtf(var + 1e-5f);
        }
    #pragma unroll
    for (int n = 0; n < 8; ++n) {
        const int o = nh * 128 + n * 16 + lw;
        const float g2 = n2g[o], b2 = n2b[o];
        #pragma unroll
        for (int m = 0; m < 2; ++m)
            #pragma unroll
            for (int r = 0; r < 4; ++r) {
                const int row = mh * 32 + m * 16 + quad * 4 + r;
                const float y = gelu_f((acc[m][n][r] - mean[m][r]) * rsv[m][r] * g2 + b2);
                ylds[row * 264 + o] = f2bf(y);
            }
    }
    __syncthreads();

    #pragma unroll
    for (int jj = 0; jj < 8; ++jj) {
        const int idx = jj * 256 + tid;
        const int row = idx >> 5, seg = idx & 31;
        const size_t g = hbase + (size_t)(t0 + row) * HC + seg * 8;
        const uint4 yv = *(const uint4*)(&ylds[row * 264 + seg * 8]);
        uint4 ov;
        ov.x = addbf2(yv.x, hv[jj].x);
        ov.y = addbf2(yv.y, hv[jj].y);
        ov.z = addbf2(yv.z, hv[jj].z);
        ov.w = addbf2(yv.w, hv[jj].w);
        *(uint4*)(hout + g) = ov;
    }
}

// ---------------------------------------------------------- proj+spline ----
__global__ __launch_bounds__(256) void proj_kernel(
    const ushort* __restrict__ hin, const ushort* __restrict__ pwbf,
    const float* __restrict__ projb, const float* __restrict__ x,
    const float* __restrict__ mask, float* __restrict__ out)
{
    __shared__ __align__(16) ushort alds[64 * 264];
    __shared__ float slds[64 * 65];
    __shared__ float red[4];

    const int tid = threadIdx.x;
    const int lane = tid & 63;
    const int wv = tid >> 6;
    const int blk = blockIdx.x;
    const int b = blk >> 6;
    const int t0 = (blk & 63) << 6;
    const size_t hbase = (size_t)b * T_LEN * HC;

    #pragma unroll
    for (int jj = 0; jj < 8; ++jj) {
        const int idx = jj * 256 + tid;
        const int row = idx >> 5, seg = idx & 31;
        short8 v = *(const short8*)(hin + hbase + (size_t)(t0 + row) * HC + seg * 8);
        *(short8*)(&alds[row * 264 + seg * 8]) = v;
    }
    __syncthreads();

    const int lw = lane & 15;
    const int quad = lane >> 4;
    floatx4 acc[4];
    #pragma unroll
    for (int n = 0; n < 4; ++n) acc[n] = (floatx4){0.f, 0.f, 0.f, 0.f};
    #pragma unroll
    for (int kt = 0; kt < 8; ++kt) {
        short8 a = *(short8*)(&alds[(wv * 16 + lw) * 264 + kt * 32 + quad * 8]);
        #pragma unroll
        for (int n = 0; n < 4; ++n) {
            short8 bb = *(const short8*)(pwbf + (n * 16 + lw) * 256 + kt * 32 + quad * 8);
            acc[n] = __builtin_amdgcn_mfma_f32_16x16x32_bf16(a, bb, acc[n], 0, 0, 0);
        }
    }
    #pragma unroll
    for (int n = 0; n < 4; ++n) {
        const int o = n * 16 + lw;
        const float pb = (o < 58) ? projb[o] : 0.f;
        #pragma unroll
        for (int r = 0; r < 4; ++r) {
            const int row = wv * 16 + quad * 4 + r;
            const float mv = mask[b * T_LEN + t0 + row];
            slds[row * 65 + o] = acc[n][r] * mv + pb;
        }
    }
    __syncthreads();

    float contrib = 0.f;
    if (tid < 128) {
        const int pos = tid >> 1;
        const int ch = tid & 1;
        const int t = t0 + pos;
        float sv[29];
        #pragma unroll
        for (int j = 0; j < 29; ++j) sv[j] = slds[pos * 65 + ch * 29 + j];
        const float x1 = x[b * 16384 + (2 + ch) * 4096 + t];

        const float SC = 0.0625f;
        float cwv[11], wdv[10], chv[11], htv[10], dvv[11];
        {
            float u[10];
            float mx = -1e30f;
            #pragma unroll
            for (int j = 0; j < 10; ++j) { u[j] = sv[j] * SC; mx = fmaxf(mx, u[j]); }
            float ssm = 0.f;
            #pragma unroll
            for (int j = 0; j < 10; ++j) { u[j] = expf(u[j] - mx); ssm += u[j]; }
            const float inv = 1.f / ssm;
            float cum = 0.f;
            cwv[0] = -5.f;
            #pragma unroll
            for (int j = 0; j < 10; ++j) {
                cum += 0.001f + 0.99f * u[j] * inv;
                cwv[j + 1] = 10.f * cum - 5.f;
            }
            cwv[10] = 5.f;
            #pragma unroll
            for (int j = 0; j < 10; ++j) wdv[j] = cwv[j + 1] - cwv[j];
        }
        {
            float u[10];
            float mx = -1e30f;
            #pragma unroll
            for (int j = 0; j < 10; ++j) { u[j] = sv[10 + j] * SC; mx = fmaxf(mx, u[j]); }
            float ssm = 0.f;
            #pragma unroll
            for (int j = 0; j < 10; ++j) { u[j] = expf(u[j] - mx); ssm += u[j]; }
            const float inv = 1.f / ssm;
            float cum = 0.f;
            chv[0] = -5.f;
            #pragma unroll
            for (int j = 0; j < 10; ++j) {
                cum += 0.001f + 0.99f * u[j] * inv;
                chv[j + 1] = 10.f * cum - 5.f;
            }
            chv[10] = 5.f;
            #pragma unroll
            for (int j = 0; j < 10; ++j) htv[j] = chv[j + 1] - chv[j];
        }
        dvv[0] = 1.f;
        dvv[10] = 1.f;
        #pragma unroll
        for (int j = 1; j <= 9; ++j) dvv[j] = 0.001f + softplus_f(sv[19 + j]);

        const bool inside = (x1 >= -5.f) && (x1 <= 5.f);
        const float xc = fminf(fmaxf(x1, -5.f), 5.f);
        float in_cw = cwv[0], in_w = wdv[0], in_ch = chv[0], in_h = htv[0];
        float dk = dvv[0], dk1 = dvv[1];
        #pragma unroll
        for (int j = 1; j < 10; ++j) {
            const bool ge = (xc >= cwv[j]);
            in_cw = ge ? cwv[j] : in_cw;
            in_w  = ge ? wdv[j] : in_w;
            in_ch = ge ? chv[j] : in_ch;
            in_h  = ge ? htv[j] : in_h;
            dk    = ge ? dvv[j] : dk;
            dk1   = ge ? dvv[j + 1] : dk1;
        }
        const float th = (xc - in_cw) / in_w;
        const float t1m = th * (1.f - th);
        const float dl = in_h / in_w;
        const float num = in_h * (dl * th * th + dk * t1m);
        const float den = dl + (dk + dk1 - 2.f * dl) * t1m;
        float yv = in_ch + num / den;
        const float omt = 1.f - th;
        const float dnum = dl * dl * (dk1 * th * th + 2.f * dl * t1m + dk * omt * omt);
        float lad = logf(dnum) - 2.f * logf(den);
        if (!inside) { yv = x1; lad = 0.f; }
        const float mv = mask[b * T_LEN + t];
        out[b * 16384 + (2 + ch) * 4096 + t] = yv * mv;
        contrib = lad * mv;
    }
    #pragma unroll
    for (int d = 32; d > 0; d >>= 1) contrib += __shfl_xor(contrib, d, 64);
    if (lane == 0) red[wv] = contrib;
    __syncthreads();
    if (tid == 0) atomicAdd(out + OUT_ELEMS + b, red[0] + red[1] + red[2] + red[3]);
}

// -------------------------------------------------------------- launch ----
extern "C" void kernel_launch(void* const* d_in, const int* in_sizes, int n_in,
                              void* d_out, int out_size, void* d_ws, size_t ws_size,
                              hipStream_t stream) {
    const float* x      = (const float*)d_in[0];
    const float* mask   = (const float*)d_in[1];
    const float* pre_w  = (const float*)d_in[2];
    const float* pre_b  = (const float*)d_in[3];
    const float* sep_w  = (const float*)d_in[4];
    const float* sep_b  = (const float*)d_in[5];
    const float* conv1w = (const float*)d_in[6];
    const float* conv1b = (const float*)d_in[7];
    const float* n1g    = (const float*)d_in[8];
    const float* n1b    = (const float*)d_in[9];
    const float* n2g    = (const float*)d_in[10];
    const float* n2b    = (const float*)d_in[11];
    const float* projw  = (const float*)d_in[12];
    const float* projb  = (const float*)d_in[13];
    float* out = (float*)d_out;

    ushort* h0   = (ushort*)d_ws;
    ushort* h1   = h0 + (size_t)NPOS * HC;
    ushort* wbf  = h1 + (size_t)NPOS * HC;
    ushort* pwbf = wbf + 4 * 256 * 256;

    prep_kernel<<<2113, 256, 0, stream>>>(conv1w, projw, x, mask, wbf, pwbf, out);

    // layer 0: fully fused (h0 = h, h1 = h_next)
    fused0_kernel<<<2048, 256, 0, stream>>>(x, h0, h1, wbf,
        pre_w, pre_b, sep_w, sep_b, conv1b, n1g, n1b, n2g, n2b, mask);

    // layers 1-3: fully fused (y stays in LDS); ping-pong, never in-place
    fused_kernel<<<2048, 256, 0, stream>>>(h1, h0, wbf + 1 * 65536,
        sep_w + 1 * 768, sep_b + 1 * 256, conv1b + 1 * 256,
        n1g + 1 * 256, n1b + 1 * 256, n2g + 1 * 256, n2b + 1 * 256, mask, 3);
    fused_kernel<<<2048, 256, 0, stream>>>(h0, h1, wbf + 2 * 65536,
        sep_w + 2 * 768, sep_b + 2 * 256, conv1b + 2 * 256,
        n1g + 2 * 256, n1b + 2 * 256, n2g + 2 * 256, n2b + 2 * 256, mask, 9);
    fused_kernel<<<2048, 256, 0, stream>>>(h1, h0, wbf + 3 * 65536,
        sep_w + 3 * 768, sep_b + 3 * 256, conv1b + 3 * 256,
        n1g + 3 * 256, n1b + 3 * 256, n2g + 3 * 256, n2b + 3 * 256, mask, 27);

    proj_kernel<<<2048, 256, 0, stream>>>(h0, pwbf, projb, x, mask, out);
}